// Round 3
// baseline (660.603 us; speedup 1.0000x reference)
//
#include <hip/hip_runtime.h>
#include <stdint.h>

// Problem constants
#define B_ 4
#define S_ 2048
#define E_ 1024
#define H_ 16
#define HD_ 64

typedef __attribute__((ext_vector_type(8))) short bf16x8;   // 8 bf16 = 4 VGPRs (MFMA A/B frag)
typedef __attribute__((ext_vector_type(4))) float f32x4;    // MFMA C/D frag

__device__ __forceinline__ ushort f2b(float f) {
    union { float f; uint32_t u; } c; c.f = f;
    return (ushort)((c.u + 0x8000u) >> 16);   // round-to-nearest (ties up)
}

// async global->LDS, 16B per lane; LDS dest = wave-uniform base + lane*16
__device__ __forceinline__ void gl2lds16(const ushort* g, const ushort* l) {
    __builtin_amdgcn_global_load_lds(
        (const __attribute__((address_space(1))) unsigned int*)g,
        (__attribute__((address_space(3))) unsigned int*)l,
        16, 0, 0);
}
__device__ __forceinline__ void gl2lds16raw(const void* g, const void* l) {
    __builtin_amdgcn_global_load_lds(
        (const __attribute__((address_space(1))) unsigned int*)g,
        (__attribute__((address_space(3))) unsigned int*)l,
        16, 0, 0);
}

// ---------------------------------------------------------------- converts
__global__ __launch_bounds__(256) void cvt_bf16(const float* __restrict__ src,
                                                ushort* __restrict__ dst, int n4) {
    int i = blockIdx.x * 256 + threadIdx.x;
    if (i < n4) {
        float4 f = ((const float4*)src)[i];
        ushort4 o;
        o.x = f2b(f.x); o.y = f2b(f.y); o.z = f2b(f.z); o.w = f2b(f.w);
        ((ushort4*)dst)[i] = o;
    }
}

// mask [B,S,S] int32 (0/1) -> bit-packed, kt-major:
// mb[((b*32 + kt)*2048 + q)*2 + w] bit c = mask[b][q][kt*64 + w*32 + c]
__global__ __launch_bounds__(256) void pack_mask(const int* __restrict__ mask,
                                                 uint32_t* __restrict__ mb) {
    int i = blockIdx.x * 256 + threadIdx.x;   // 16777216 threads
    unsigned long long bal = __ballot(mask[i] == 1);
    int lane = threadIdx.x & 63;
    if (lane < 2) {
        int b = i >> 22, q = (i >> 11) & 2047, c = i & 2047;
        int kt = c >> 6;
        mb[((uint64_t)(b * 32 + kt) * 2048 + q) * 2 + lane] =
            (lane == 0) ? (uint32_t)bal : (uint32_t)(bal >> 32);
    }
}

// ---------------------------------------------------------------- GEMM core
template <int KD>
__device__ __forceinline__ void gemm_bt_core(
    const ushort* __restrict__ A, const ushort* __restrict__ Bm,
    int m0, int n0, ushort* As, ushort* Bs, f32x4 (&acc)[4][4])
{
    const int tid  = threadIdx.x;
    const int lane = tid & 63;
    const int wave = tid >> 6;
    const int wm = wave >> 1, wn = wave & 1;
    const int fr = lane & 15;
    const int fk = (lane >> 4) * 8;
    const int lrow = lane >> 2;
    const int lk   = (lane & 3) * 8;

    const f32x4 fz = {0.f, 0.f, 0.f, 0.f};
#pragma unroll
    for (int i = 0; i < 4; ++i)
#pragma unroll
        for (int j = 0; j < 4; ++j) acc[i][j] = fz;

    for (int kt = 0; kt < KD / 32; ++kt) {
        const int k0 = kt * 32;
        __syncthreads();
#pragma unroll
        for (int t = 0; t < 2; ++t) {
            const int r0 = t * 64 + wave * 16;
            gl2lds16(&A [(uint64_t)(m0 + r0 + lrow) * KD + k0 + lk], &As[r0 * 32]);
            gl2lds16(&Bm[(uint64_t)(n0 + r0 + lrow) * KD + k0 + lk], &Bs[r0 * 32]);
        }
        __syncthreads();
        bf16x8 af[4], bfr[4];
#pragma unroll
        for (int i = 0; i < 4; ++i)
            af[i] = *(const bf16x8*)&As[(wm * 64 + i * 16 + fr) * 32 + fk];
#pragma unroll
        for (int j = 0; j < 4; ++j)
            bfr[j] = *(const bf16x8*)&Bs[(wn * 64 + j * 16 + fr) * 32 + fk];
#pragma unroll
        for (int i = 0; i < 4; ++i)
#pragma unroll
            for (int j = 0; j < 4; ++j)
                acc[i][j] = __builtin_amdgcn_mfma_f32_16x16x32_bf16(af[i], bfr[j], acc[i][j], 0, 0, 0);
    }
}

// ---------------------------------------------------------------- QKV GEMM
// 1D grid 1536, XCD swizzle: 3 N-tiles pinned per XCD (Wqkv slice resident in L2)
__global__ __launch_bounds__(256) void qkv_gemm(
    const ushort* __restrict__ xb, const ushort* __restrict__ wb,
    const float* __restrict__ bqkv,
    ushort* __restrict__ qo, ushort* __restrict__ ko, ushort* __restrict__ vto)
{
    __shared__ ushort As[128 * 32];
    __shared__ ushort Bs[128 * 32];
    f32x4 acc[4][4];
    const int i = blockIdx.x;
    const int c = i & 7, t = i >> 3;          // t in [0,192)
    const int n0 = (c + 8 * (t % 3)) * 128;   // 24 N-tiles, n0%8-class pinned to XCD c
    const int m0 = (t / 3) * 128;             // 64 M-tiles
    gemm_bt_core<1024>(xb, wb, m0, n0, As, Bs, acc);

    const int lane = threadIdx.x & 63, wave = threadIdx.x >> 6;
    const int wm = wave >> 1, wn = wave & 1;
    const int col = lane & 15, rg = lane >> 4;
#pragma unroll
    for (int j = 0; j < 4; ++j) {
        const int n = n0 + wn * 64 + j * 16 + col;
        const int h = n / 192, f = n % 192;
        const float bias = bqkv[n];
#pragma unroll
        for (int i2 = 0; i2 < 4; ++i2) {
            const int mbase = m0 + wm * 64 + i2 * 16 + rg * 4;
            if (f < 128) {
#pragma unroll
                for (int v = 0; v < 4; ++v) {
                    const int m = mbase + v;
                    const int b = m >> 11, s = m & 2047;
                    const float val = acc[i2][j][v] + bias;
                    if (f < 64) qo[((uint64_t)(b * 16 + h) * 2048 + s) * 64 + f]        = f2b(val * 0.125f);
                    else        ko[((uint64_t)(b * 16 + h) * 2048 + s) * 64 + (f - 64)] = f2b(val);
                }
            } else {
                const int b = mbase >> 11, s = mbase & 2047;
                ushort4 pk;
                pk.x = f2b(acc[i2][j][0] + bias);
                pk.y = f2b(acc[i2][j][1] + bias);
                pk.z = f2b(acc[i2][j][2] + bias);
                pk.w = f2b(acc[i2][j][3] + bias);
                *(ushort4*)&vto[((uint64_t)(b * 16 + h) * 64 + (f - 128)) * 2048 + s] = pk;
            }
        }
    }
}

// ---------------------------------------------------------------- flash attention v3
// XCD swizzle: all 16 q-blocks of one (b,h) co-resident on one XCD (K/V stay in its L2).
// K/V register-prefetch pipeline: global->VGPR for kt+1 during consume of kt,
// VGPR->LDS (ds_write_b128) at top of kt+1 -> both barriers are cheap drains.
__global__ __launch_bounds__(256, 4) void attn_kernel(
    const ushort* __restrict__ qa, const ushort* __restrict__ ka,
    const ushort* __restrict__ vta, const uint32_t* __restrict__ mbits,
    ushort* __restrict__ ctxo)
{
    __shared__ __align__(16) ushort SMEM[128 * 64];  // 16 KB: Q staging / per-wave P / ctx staging
    __shared__ __align__(16) ushort Ks[64 * 64];     // 8 KB
    __shared__ __align__(16) ushort Vts[64 * 64];    // 8 KB [d][k]
    __shared__ __align__(16) uint32_t Ms[2][256];    // 2 KB mask bits (double-buffered)

    const int bid = blockIdx.x;
    const int xc = bid & 7, t = bid >> 3;     // XCD class
    const int qb = t & 15;
    const int bh = xc + 8 * (t >> 4);         // bh % 8 == xc -> same-XCD K/V reuse
    const int b = bh >> 4;
    const int tid = threadIdx.x, lane = tid & 63, wave = tid >> 6;
    const int col = lane & 15, rg = lane >> 4;

    const uint64_t bhoff = (uint64_t)bh * (S_ * 64);
    const ushort* qp = qa + bhoff + (uint64_t)qb * 128 * 64;
    const ushort* kp = ka + bhoff;
    const ushort* vp = vta + bhoff;                       // [64][2048]
    const uint32_t* mkb = mbits + ((uint64_t)(b * 32) * 2048 + qb * 128) * 2;  // +kt*4096

    // per-thread staging offsets (match gl2lds-style contiguous layout)
    const int koff0 = (wave * 2 + 0) * 512 + lane * 8;    // K/V LDS element offset, t=0
    const int koff1 = (wave * 2 + 1) * 512 + lane * 8;    // t=1
    const int vrow0 = (wave * 2 + 0) * 8 + (lane >> 3);   // V global row (d), t=0
    const int vrow1 = (wave * 2 + 1) * 8 + (lane >> 3);
    const int vcol  = (lane & 7) * 8;                     // V global col base (k within tile)

    // stage Q tile (each wave its own 4 KB slice)
#pragma unroll
    for (int t4 = 0; t4 < 4; ++t4) {
        const int o = (wave * 4 + t4) * 512;
        gl2lds16(&qp[o + lane * 8], &SMEM[o]);
    }
    // prefetch kt=0 K/V into registers
    int4 kr0 = *(const int4*)&kp[koff0];
    int4 kr1 = *(const int4*)&kp[koff1];
    int4 vr0 = *(const int4*)&vp[(uint64_t)vrow0 * S_ + vcol];
    int4 vr1 = *(const int4*)&vp[(uint64_t)vrow1 * S_ + vcol];
    if (wave == 0) gl2lds16raw(mkb + lane * 4, &Ms[0][0]);
    __syncthreads();                         // Q + mask visible

    bf16x8 aq[2][2];
#pragma unroll
    for (int i = 0; i < 2; ++i)
#pragma unroll
        for (int k2 = 0; k2 < 2; ++k2)
            aq[i][k2] = *(const bf16x8*)&SMEM[(wave * 32 + i * 16 + col) * 64 + k2 * 32 + rg * 8];

    const f32x4 fz = {0.f, 0.f, 0.f, 0.f};
    f32x4 acc[4][2];                      // ctx^T: row=d, col=q
#pragma unroll
    for (int dt = 0; dt < 4; ++dt)
#pragma unroll
        for (int i = 0; i < 2; ++i) acc[dt][i] = fz;
    float lsum[2][4];
#pragma unroll
    for (int i = 0; i < 2; ++i)
#pragma unroll
        for (int v = 0; v < 4; ++v) lsum[i][v] = 0.f;

    ushort* Ps = &SMEM[wave * 2048];      // wave-private 32x64 P tile (XOR-swizzled)

    for (int kt = 0; kt < 32; ++kt) {
        // commit prefetched K/V tile to LDS
        *(int4*)&Ks[koff0]  = kr0;
        *(int4*)&Ks[koff1]  = kr1;
        *(int4*)&Vts[koff0] = vr0;
        *(int4*)&Vts[koff1] = vr1;
        __syncthreads();                  // writes visible (no vm outstanding -> cheap)

        // issue prefetch for kt+1 (lands during this consume phase)
        if (kt < 31) {
            const uint64_t knext = (uint64_t)(kt + 1) * 4096;
            kr0 = *(const int4*)&kp[knext + koff0];
            kr1 = *(const int4*)&kp[knext + koff1];
            vr0 = *(const int4*)&vp[(uint64_t)vrow0 * S_ + (kt + 1) * 64 + vcol];
            vr1 = *(const int4*)&vp[(uint64_t)vrow1 * S_ + (kt + 1) * 64 + vcol];
            if (wave == 0) gl2lds16raw(mkb + (uint64_t)(kt + 1) * 4096 + lane * 4,
                                       &Ms[(kt + 1) & 1][0]);
        }

        // scores S[q][k] (C-layout: row=q, col=k)
        f32x4 sc[2][4];
#pragma unroll
        for (int j = 0; j < 4; ++j) {
            bf16x8 bk0 = *(const bf16x8*)&Ks[(j * 16 + col) * 64 + rg * 8];
            bf16x8 bk1 = *(const bf16x8*)&Ks[(j * 16 + col) * 64 + 32 + rg * 8];
#pragma unroll
            for (int i = 0; i < 2; ++i) {
                f32x4 z = __builtin_amdgcn_mfma_f32_16x16x32_bf16(aq[i][0], bk0, fz, 0, 0, 0);
                sc[i][j] = __builtin_amdgcn_mfma_f32_16x16x32_bf16(aq[i][1], bk1, z, 0, 0, 0);
            }
        }

        // mask + exp (fixed m=0), partial sums, swizzled P store
        const uint32_t* msl = &Ms[kt & 1][wave * 64];
#pragma unroll
        for (int i = 0; i < 2; ++i) {
#pragma unroll
            for (int v = 0; v < 4; ++v) {
                const int prow = i * 16 + rg * 4 + v;
                const uint2 mw = *(const uint2*)&msl[prow * 2];
                const int sw = prow & 7;
                float ts = 0.f;
#pragma unroll
                for (int j = 0; j < 4; ++j) {
                    const uint32_t w = (j & 2) ? mw.y : mw.x;
                    const uint32_t bit = (w >> ((j & 1) * 16 + col)) & 1u;
                    const float pj = bit ? 1.0f : __expf(sc[i][j][v]);
                    ts += pj;
                    const int g = (j * 2 + (col >> 3)) ^ sw;
                    Ps[prow * 64 + g * 8 + (col & 7)] = f2b(pj);
                }
                lsum[i][v] += ts;
            }
        }

        // PV (transposed): acc[d][q] += Vt[d][k] * P[q][k]
        bf16x8 bp[2][2];
#pragma unroll
        for (int i = 0; i < 2; ++i)
#pragma unroll
            for (int k2 = 0; k2 < 2; ++k2)
                bp[i][k2] = *(const bf16x8*)&Ps[(i * 16 + col) * 64 + (((k2 * 4 + rg) ^ (col & 7)) << 3)];
#pragma unroll
        for (int dt = 0; dt < 4; ++dt) {
            bf16x8 av0 = *(const bf16x8*)&Vts[(dt * 16 + col) * 64 + rg * 8];
            bf16x8 av1 = *(const bf16x8*)&Vts[(dt * 16 + col) * 64 + 32 + rg * 8];
#pragma unroll
            for (int i = 0; i < 2; ++i) {
                acc[dt][i] = __builtin_amdgcn_mfma_f32_16x16x32_bf16(av0, bp[i][0], acc[dt][i], 0, 0, 0);
                acc[dt][i] = __builtin_amdgcn_mfma_f32_16x16x32_bf16(av1, bp[i][1], acc[dt][i], 0, 0, 0);
            }
        }
        __syncthreads();                  // LDS reads done; also drains kt+1 vm loads (had a full phase)
    }

    // reduce l over the 16 col-lanes, broadcast 1/l per acc column
    float linv[2];
#pragma unroll
    for (int i = 0; i < 2; ++i) {
#pragma unroll
        for (int v = 0; v < 4; ++v) {
            float ts = lsum[i][v];
            ts += __shfl_xor(ts, 1);
            ts += __shfl_xor(ts, 2);
            ts += __shfl_xor(ts, 4);
            ts += __shfl_xor(ts, 8);
            lsum[i][v] = ts;
        }
        const int src = (col >> 2) << 4;
        const float l0 = __shfl(lsum[i][0], src);
        const float l1 = __shfl(lsum[i][1], src);
        const float l2 = __shfl(lsum[i][2], src);
        const float l3 = __shfl(lsum[i][3], src);
        const int sel = col & 3;
        const float lc = (sel == 0) ? l0 : (sel == 1) ? l1 : (sel == 2) ? l2 : l3;
        linv[i] = 1.0f / lc;
    }

    // transpose ctx^T back through SMEM (swizzled) for coalesced global store
#pragma unroll
    for (int dt = 0; dt < 4; ++dt)
#pragma unroll
        for (int i = 0; i < 2; ++i) {
            const int q = wave * 32 + i * 16 + col;
            const int d = dt * 16 + rg * 4;
            const int gg = (d >> 3) ^ (q & 7);
            ushort4 pk;
            pk.x = f2b(acc[dt][i][0] * linv[i]);
            pk.y = f2b(acc[dt][i][1] * linv[i]);
            pk.z = f2b(acc[dt][i][2] * linv[i]);
            pk.w = f2b(acc[dt][i][3] * linv[i]);
            *(ushort4*)&SMEM[q * 64 + gg * 8 + (d & 7)] = pk;
        }
    __syncthreads();
    const int h = bh & 15;
    const uint64_t obase = (uint64_t)(b * S_ + qb * 128) * E_ + (uint64_t)h * 64;
#pragma unroll
    for (int t4 = 0; t4 < 4; ++t4) {
        const int id = tid + t4 * 256;
        const int r = id >> 3, c8 = id & 7;
        *(bf16x8*)&ctxo[obase + (uint64_t)r * E_ + c8 * 8] =
            *(const bf16x8*)&SMEM[r * 64 + ((c8 ^ (r & 7)) << 3)];
    }
}

// ---------------------------------------------------------------- output GEMM
// 1D grid 512, XCD swizzle: exactly one N-tile per XCD (Wo slice resident in L2)
__global__ __launch_bounds__(256) void out_gemm(
    const ushort* __restrict__ ctxb, const ushort* __restrict__ wob,
    const float* __restrict__ bo, float* __restrict__ out)
{
    __shared__ ushort As[128 * 32];
    __shared__ ushort Bs[128 * 32];
    f32x4 acc[4][4];
    const int i = blockIdx.x;
    const int n0 = (i & 7) * 128;             // 8 N-tiles, one per XCD
    const int m0 = (i >> 3) * 128;            // 64 M-tiles
    gemm_bt_core<1024>(ctxb, wob, m0, n0, As, Bs, acc);

    const int lane = threadIdx.x & 63, wave = threadIdx.x >> 6;
    const int wm = wave >> 1, wn = wave & 1;
    const int col = lane & 15, rg = lane >> 4;
#pragma unroll
    for (int j = 0; j < 4; ++j) {
        const int n = n0 + wn * 64 + j * 16 + col;
        const float bias = bo[n];
#pragma unroll
        for (int i2 = 0; i2 < 4; ++i2) {
            const int mb2 = m0 + wm * 64 + i2 * 16 + rg * 4;
#pragma unroll
            for (int v = 0; v < 4; ++v)
                out[(uint64_t)(mb2 + v) * 1024 + n] = acc[i2][j][v] + bias;
        }
    }
}

// ---------------------------------------------------------------- launch
extern "C" void kernel_launch(void* const* d_in, const int* in_sizes, int n_in,
                              void* d_out, int out_size, void* d_ws, size_t ws_size,
                              hipStream_t stream)
{
    const float* x    = (const float*)d_in[0];
    const int*   mask = (const int*)d_in[1];
    const float* Wqkv = (const float*)d_in[2];
    const float* bqkv = (const float*)d_in[3];
    const float* Wo   = (const float*)d_in[4];
    const float* bo   = (const float*)d_in[5];
    float* out = (float*)d_out;

    char* p = (char*)d_ws;
    ushort* xb  = (ushort*)p; p += (size_t)8388608 * 2;   // x bf16 [8192][1024]
    ushort* wqb = (ushort*)p; p += (size_t)3145728 * 2;   // Wqkv bf16 [3072][1024]
    ushort* wob = (ushort*)p; p += (size_t)1048576 * 2;   // Wo bf16 [1024][1024]
    ushort* qo  = (ushort*)p; p += (size_t)8388608 * 2;   // Q bf16 [bh][s][64] (pre-scaled)
    ushort* ko  = (ushort*)p; p += (size_t)8388608 * 2;   // K bf16 [bh][s][64]
    ushort* vto = (ushort*)p; p += (size_t)8388608 * 2;   // V^T bf16 [bh][64][s]
    ushort* ctx = (ushort*)p; p += (size_t)8388608 * 2;   // ctx bf16 [8192][1024]
    uint32_t* mb = (uint32_t*)p;                          // packed mask bits (kt-major), 2 MB

    cvt_bf16<<<8192, 256, 0, stream>>>(x, xb, 2097152);
    cvt_bf16<<<3072, 256, 0, stream>>>(Wqkv, wqb, 786432);
    cvt_bf16<<<1024, 256, 0, stream>>>(Wo, wob, 262144);
    pack_mask<<<65536, 256, 0, stream>>>(mask, mb);
    qkv_gemm<<<1536, 256, 0, stream>>>(xb, wqb, bqkv, qo, ko, vto);
    attn_kernel<<<1024, 256, 0, stream>>>(qo, ko, vto, mb, ctx);
    out_gemm<<<512, 256, 0, stream>>>(ctx, wob, bo, out);
}

// Round 4
// 418.539 us; speedup vs baseline: 1.5784x; 1.5784x over previous
//
#include <hip/hip_runtime.h>
#include <stdint.h>

// Problem constants
#define B_ 4
#define S_ 2048
#define E_ 1024
#define H_ 16
#define HD_ 64

typedef __attribute__((ext_vector_type(8))) short bf16x8;   // 8 bf16 = 4 VGPRs (MFMA A/B frag)
typedef __attribute__((ext_vector_type(4))) float f32x4;    // MFMA C/D frag

__device__ __forceinline__ ushort f2b(float f) {
    union { float f; uint32_t u; } c; c.f = f;
    return (ushort)((c.u + 0x8000u) >> 16);   // round-to-nearest (ties up)
}

// async global->LDS, 16B per lane; LDS dest = wave-uniform base + lane*16
__device__ __forceinline__ void gl2lds16(const ushort* g, const ushort* l) {
    __builtin_amdgcn_global_load_lds(
        (const __attribute__((address_space(1))) unsigned int*)g,
        (__attribute__((address_space(3))) unsigned int*)l,
        16, 0, 0);
}
__device__ __forceinline__ void gl2lds16raw(const void* g, const void* l) {
    __builtin_amdgcn_global_load_lds(
        (const __attribute__((address_space(1))) unsigned int*)g,
        (__attribute__((address_space(3))) unsigned int*)l,
        16, 0, 0);
}

// ---------------------------------------------------------------- converts
__global__ __launch_bounds__(256) void cvt_bf16(const float* __restrict__ src,
                                                ushort* __restrict__ dst, int n4) {
    int i = blockIdx.x * 256 + threadIdx.x;
    if (i < n4) {
        float4 f = ((const float4*)src)[i];
        ushort4 o;
        o.x = f2b(f.x); o.y = f2b(f.y); o.z = f2b(f.z); o.w = f2b(f.w);
        ((ushort4*)dst)[i] = o;
    }
}

// mask [B,S,S] int32 (0/1) -> bit-packed, kt-major:
// mb[((b*32 + kt)*2048 + q)*2 + w] bit c = mask[b][q][kt*64 + w*32 + c]
__global__ __launch_bounds__(256) void pack_mask(const int* __restrict__ mask,
                                                 uint32_t* __restrict__ mb) {
    int i = blockIdx.x * 256 + threadIdx.x;   // 16777216 threads
    unsigned long long bal = __ballot(mask[i] == 1);
    int lane = threadIdx.x & 63;
    if (lane < 2) {
        int b = i >> 22, q = (i >> 11) & 2047, c = i & 2047;
        int kt = c >> 6;
        mb[((uint64_t)(b * 32 + kt) * 2048 + q) * 2 + lane] =
            (lane == 0) ? (uint32_t)bal : (uint32_t)(bal >> 32);
    }
}

// ---------------------------------------------------------------- GEMM core
template <int KD>
__device__ __forceinline__ void gemm_bt_core(
    const ushort* __restrict__ A, const ushort* __restrict__ Bm,
    int m0, int n0, ushort* As, ushort* Bs, f32x4 (&acc)[4][4])
{
    const int tid  = threadIdx.x;
    const int lane = tid & 63;
    const int wave = tid >> 6;
    const int wm = wave >> 1, wn = wave & 1;
    const int fr = lane & 15;
    const int fk = (lane >> 4) * 8;
    const int lrow = lane >> 2;
    const int lk   = (lane & 3) * 8;

    const f32x4 fz = {0.f, 0.f, 0.f, 0.f};
#pragma unroll
    for (int i = 0; i < 4; ++i)
#pragma unroll
        for (int j = 0; j < 4; ++j) acc[i][j] = fz;

    for (int kt = 0; kt < KD / 32; ++kt) {
        const int k0 = kt * 32;
        __syncthreads();
#pragma unroll
        for (int t = 0; t < 2; ++t) {
            const int r0 = t * 64 + wave * 16;
            gl2lds16(&A [(uint64_t)(m0 + r0 + lrow) * KD + k0 + lk], &As[r0 * 32]);
            gl2lds16(&Bm[(uint64_t)(n0 + r0 + lrow) * KD + k0 + lk], &Bs[r0 * 32]);
        }
        __syncthreads();
        bf16x8 af[4], bfr[4];
#pragma unroll
        for (int i = 0; i < 4; ++i)
            af[i] = *(const bf16x8*)&As[(wm * 64 + i * 16 + fr) * 32 + fk];
#pragma unroll
        for (int j = 0; j < 4; ++j)
            bfr[j] = *(const bf16x8*)&Bs[(wn * 64 + j * 16 + fr) * 32 + fk];
#pragma unroll
        for (int i = 0; i < 4; ++i)
#pragma unroll
            for (int j = 0; j < 4; ++j)
                acc[i][j] = __builtin_amdgcn_mfma_f32_16x16x32_bf16(af[i], bfr[j], acc[i][j], 0, 0, 0);
    }
}

// ---------------------------------------------------------------- QKV GEMM
__global__ __launch_bounds__(256) void qkv_gemm(
    const ushort* __restrict__ xb, const ushort* __restrict__ wb,
    const float* __restrict__ bqkv,
    ushort* __restrict__ qo, ushort* __restrict__ ko, ushort* __restrict__ vto)
{
    __shared__ ushort As[128 * 32];
    __shared__ ushort Bs[128 * 32];
    f32x4 acc[4][4];
    const int i = blockIdx.x;
    const int c = i & 7, t = i >> 3;          // t in [0,192)
    const int n0 = (c + 8 * (t % 3)) * 128;   // 24 N-tiles
    const int m0 = (t / 3) * 128;             // 64 M-tiles
    gemm_bt_core<1024>(xb, wb, m0, n0, As, Bs, acc);

    const int lane = threadIdx.x & 63, wave = threadIdx.x >> 6;
    const int wm = wave >> 1, wn = wave & 1;
    const int col = lane & 15, rg = lane >> 4;
#pragma unroll
    for (int j = 0; j < 4; ++j) {
        const int n = n0 + wn * 64 + j * 16 + col;
        const int h = n / 192, f = n % 192;
        const float bias = bqkv[n];
#pragma unroll
        for (int i2 = 0; i2 < 4; ++i2) {
            const int mbase = m0 + wm * 64 + i2 * 16 + rg * 4;
            if (f < 128) {
#pragma unroll
                for (int v = 0; v < 4; ++v) {
                    const int m = mbase + v;
                    const int b = m >> 11, s = m & 2047;
                    const float val = acc[i2][j][v] + bias;
                    if (f < 64) qo[((uint64_t)(b * 16 + h) * 2048 + s) * 64 + f]        = f2b(val * 0.125f);
                    else        ko[((uint64_t)(b * 16 + h) * 2048 + s) * 64 + (f - 64)] = f2b(val);
                }
            } else {
                const int b = mbase >> 11, s = mbase & 2047;
                ushort4 pk;
                pk.x = f2b(acc[i2][j][0] + bias);
                pk.y = f2b(acc[i2][j][1] + bias);
                pk.z = f2b(acc[i2][j][2] + bias);
                pk.w = f2b(acc[i2][j][3] + bias);
                *(ushort4*)&vto[((uint64_t)(b * 16 + h) * 64 + (f - 128)) * 2048 + s] = pk;
            }
        }
    }
}

// ---------------------------------------------------------------- flash attention v4
// r2 substrate (natural bid order, global_load_lds staging, m=0 softmax) +
// K/V/mask LDS DOUBLE-BUFFER with ONE barrier per kt: prefetch kt+1 issued
// before consuming kt, so the barrier's vmcnt(0) drain waits on loads that
// had a full compute phase to land. No per-thread K/V registers (no spill).
__global__ __launch_bounds__(256, 3) void attn_kernel(
    const ushort* __restrict__ qa, const ushort* __restrict__ ka,
    const ushort* __restrict__ vta, const uint32_t* __restrict__ mbits,
    ushort* __restrict__ ctxo)
{
    __shared__ __align__(16) ushort SMEM[128 * 64];    // 16 KB: Q stage / per-wave P / ctx stage
    __shared__ __align__(16) ushort Ks[2][64 * 64];    // 16 KB double-buffered K
    __shared__ __align__(16) ushort Vts[2][64 * 64];   // 16 KB double-buffered V^T [d][k]
    __shared__ __align__(16) uint32_t Ms[2][256];      // 2 KB mask bits, double-buffered

    const int bid = blockIdx.x;
    const int qb = bid & 15;                  // natural r2 order: same-bh blocks adjacent
    const int bh = bid >> 4;
    const int b = bh >> 4;
    const int tid = threadIdx.x, lane = tid & 63, wave = tid >> 6;
    const int col = lane & 15, rg = lane >> 4;

    const uint64_t bhoff = (uint64_t)bh * (S_ * 64);
    const ushort* qp = qa + bhoff + (uint64_t)qb * 128 * 64;
    const ushort* kp = ka + bhoff;
    const ushort* vp = vta + bhoff;                       // [64][2048]
    const uint32_t* mkb = mbits + ((uint64_t)(b * 32) * 2048 + qb * 128) * 2;  // +kt*4096

    // stage Q tile (each wave its own 4 KB slice)
#pragma unroll
    for (int t4 = 0; t4 < 4; ++t4) {
        const int o = (wave * 4 + t4) * 512;
        gl2lds16(&qp[o + lane * 8], &SMEM[o]);
    }
    // prefetch kt=0 K/V/mask into buffer 0
#pragma unroll
    for (int t = 0; t < 2; ++t) {
        const int o = (wave * 2 + t) * 512;
        gl2lds16(&kp[o + lane * 8], &Ks[0][o]);
        const int r0 = (wave * 2 + t) * 8;
        gl2lds16(&vp[(uint64_t)(r0 + (lane >> 3)) * S_ + (lane & 7) * 8], &Vts[0][r0 * 64]);
    }
    if (wave == 0) gl2lds16raw(mkb + lane * 4, &Ms[0][0]);
    __syncthreads();

    bf16x8 aq[2][2];
#pragma unroll
    for (int i = 0; i < 2; ++i)
#pragma unroll
        for (int k2 = 0; k2 < 2; ++k2)
            aq[i][k2] = *(const bf16x8*)&SMEM[(wave * 32 + i * 16 + col) * 64 + k2 * 32 + rg * 8];

    const f32x4 fz = {0.f, 0.f, 0.f, 0.f};
    f32x4 acc[4][2];                      // ctx^T: row=d, col=q
#pragma unroll
    for (int dt = 0; dt < 4; ++dt)
#pragma unroll
        for (int i = 0; i < 2; ++i) acc[dt][i] = fz;
    float lsum[2][4];
#pragma unroll
    for (int i = 0; i < 2; ++i)
#pragma unroll
        for (int v = 0; v < 4; ++v) lsum[i][v] = 0.f;

    ushort* Ps = &SMEM[wave * 2048];      // wave-private 32x64 P tile (XOR-swizzled)

    for (int kt = 0; kt < 32; ++kt) {
        const int buf = kt & 1;
        // issue prefetch for kt+1 into the other buffer (lands during this phase)
        if (kt < 31) {
            const uint64_t knext = (uint64_t)(kt + 1) * 4096;
#pragma unroll
            for (int t = 0; t < 2; ++t) {
                const int o = (wave * 2 + t) * 512;
                gl2lds16(&kp[knext + o + lane * 8], &Ks[buf ^ 1][o]);
                const int r0 = (wave * 2 + t) * 8;
                gl2lds16(&vp[(uint64_t)(r0 + (lane >> 3)) * S_ + (kt + 1) * 64 + (lane & 7) * 8],
                         &Vts[buf ^ 1][r0 * 64]);
            }
            if (wave == 0) gl2lds16raw(mkb + (uint64_t)(kt + 1) * 4096 + lane * 4,
                                       &Ms[buf ^ 1][0]);
        }

        // scores S[q][k] (C-layout: row=q, col=k)
        f32x4 sc[2][4];
#pragma unroll
        for (int j = 0; j < 4; ++j) {
            bf16x8 bk0 = *(const bf16x8*)&Ks[buf][(j * 16 + col) * 64 + rg * 8];
            bf16x8 bk1 = *(const bf16x8*)&Ks[buf][(j * 16 + col) * 64 + 32 + rg * 8];
#pragma unroll
            for (int i = 0; i < 2; ++i) {
                f32x4 z = __builtin_amdgcn_mfma_f32_16x16x32_bf16(aq[i][0], bk0, fz, 0, 0, 0);
                sc[i][j] = __builtin_amdgcn_mfma_f32_16x16x32_bf16(aq[i][1], bk1, z, 0, 0, 0);
            }
        }

        // mask + exp (fixed m=0), partial sums, swizzled P store
        const uint32_t* msl = &Ms[buf][wave * 64];
#pragma unroll
        for (int i = 0; i < 2; ++i) {
#pragma unroll
            for (int v = 0; v < 4; ++v) {
                const int prow = i * 16 + rg * 4 + v;
                const uint2 mw = *(const uint2*)&msl[prow * 2];
                const int sw = prow & 7;
                float ts = 0.f;
#pragma unroll
                for (int j = 0; j < 4; ++j) {
                    const uint32_t w = (j & 2) ? mw.y : mw.x;
                    const uint32_t bit = (w >> ((j & 1) * 16 + col)) & 1u;
                    const float pj = bit ? 1.0f : __expf(sc[i][j][v]);
                    ts += pj;
                    const int g = (j * 2 + (col >> 3)) ^ sw;
                    Ps[prow * 64 + g * 8 + (col & 7)] = f2b(pj);
                }
                lsum[i][v] += ts;
            }
        }

        // PV (transposed): acc[d][q] += Vt[d][k] * P[q][k]
        bf16x8 bp[2][2];
#pragma unroll
        for (int i = 0; i < 2; ++i)
#pragma unroll
            for (int k2 = 0; k2 < 2; ++k2)
                bp[i][k2] = *(const bf16x8*)&Ps[(i * 16 + col) * 64 + (((k2 * 4 + rg) ^ (col & 7)) << 3)];
#pragma unroll
        for (int dt = 0; dt < 4; ++dt) {
            bf16x8 av0 = *(const bf16x8*)&Vts[buf][(dt * 16 + col) * 64 + rg * 8];
            bf16x8 av1 = *(const bf16x8*)&Vts[buf][(dt * 16 + col) * 64 + 32 + rg * 8];
#pragma unroll
            for (int i = 0; i < 2; ++i) {
                acc[dt][i] = __builtin_amdgcn_mfma_f32_16x16x32_bf16(av0, bp[i][0], acc[dt][i], 0, 0, 0);
                acc[dt][i] = __builtin_amdgcn_mfma_f32_16x16x32_bf16(av1, bp[i][1], acc[dt][i], 0, 0, 0);
            }
        }
        __syncthreads();   // single barrier: drains kt+1 prefetch (full phase old) + LDS reads
    }

    // reduce l over the 16 col-lanes, broadcast 1/l per acc column
    float linv[2];
#pragma unroll
    for (int i = 0; i < 2; ++i) {
#pragma unroll
        for (int v = 0; v < 4; ++v) {
            float ts = lsum[i][v];
            ts += __shfl_xor(ts, 1);
            ts += __shfl_xor(ts, 2);
            ts += __shfl_xor(ts, 4);
            ts += __shfl_xor(ts, 8);
            lsum[i][v] = ts;
        }
        const int src = (col >> 2) << 4;
        const float l0 = __shfl(lsum[i][0], src);
        const float l1 = __shfl(lsum[i][1], src);
        const float l2 = __shfl(lsum[i][2], src);
        const float l3 = __shfl(lsum[i][3], src);
        const int sel = col & 3;
        const float lc = (sel == 0) ? l0 : (sel == 1) ? l1 : (sel == 2) ? l2 : l3;
        linv[i] = 1.0f / lc;
    }

    // transpose ctx^T back through SMEM (swizzled) for coalesced global store
#pragma unroll
    for (int dt = 0; dt < 4; ++dt)
#pragma unroll
        for (int i = 0; i < 2; ++i) {
            const int q = wave * 32 + i * 16 + col;
            const int d = dt * 16 + rg * 4;
            const int gg = (d >> 3) ^ (q & 7);
            ushort4 pk;
            pk.x = f2b(acc[dt][i][0] * linv[i]);
            pk.y = f2b(acc[dt][i][1] * linv[i]);
            pk.z = f2b(acc[dt][i][2] * linv[i]);
            pk.w = f2b(acc[dt][i][3] * linv[i]);
            *(ushort4*)&SMEM[q * 64 + gg * 8 + (d & 7)] = pk;
        }
    __syncthreads();
    const int h = bh & 15;
    const uint64_t obase = (uint64_t)(b * S_ + qb * 128) * E_ + (uint64_t)h * 64;
#pragma unroll
    for (int t4 = 0; t4 < 4; ++t4) {
        const int id = tid + t4 * 256;
        const int r = id >> 3, c8 = id & 7;
        *(bf16x8*)&ctxo[obase + (uint64_t)r * E_ + c8 * 8] =
            *(const bf16x8*)&SMEM[r * 64 + ((c8 ^ (r & 7)) << 3)];
    }
}

// ---------------------------------------------------------------- output GEMM
__global__ __launch_bounds__(256) void out_gemm(
    const ushort* __restrict__ ctxb, const ushort* __restrict__ wob,
    const float* __restrict__ bo, float* __restrict__ out)
{
    __shared__ ushort As[128 * 32];
    __shared__ ushort Bs[128 * 32];
    f32x4 acc[4][4];
    const int i = blockIdx.x;
    const int n0 = (i & 7) * 128;             // 8 N-tiles
    const int m0 = (i >> 3) * 128;            // 64 M-tiles
    gemm_bt_core<1024>(ctxb, wob, m0, n0, As, Bs, acc);

    const int lane = threadIdx.x & 63, wave = threadIdx.x >> 6;
    const int wm = wave >> 1, wn = wave & 1;
    const int col = lane & 15, rg = lane >> 4;
#pragma unroll
    for (int j = 0; j < 4; ++j) {
        const int n = n0 + wn * 64 + j * 16 + col;
        const float bias = bo[n];
#pragma unroll
        for (int i2 = 0; i2 < 4; ++i2) {
            const int mb2 = m0 + wm * 64 + i2 * 16 + rg * 4;
#pragma unroll
            for (int v = 0; v < 4; ++v)
                out[(uint64_t)(mb2 + v) * 1024 + n] = acc[i2][j][v] + bias;
        }
    }
}

// ---------------------------------------------------------------- launch
extern "C" void kernel_launch(void* const* d_in, const int* in_sizes, int n_in,
                              void* d_out, int out_size, void* d_ws, size_t ws_size,
                              hipStream_t stream)
{
    const float* x    = (const float*)d_in[0];
    const int*   mask = (const int*)d_in[1];
    const float* Wqkv = (const float*)d_in[2];
    const float* bqkv = (const float*)d_in[3];
    const float* Wo   = (const float*)d_in[4];
    const float* bo   = (const float*)d_in[5];
    float* out = (float*)d_out;

    char* p = (char*)d_ws;
    ushort* xb  = (ushort*)p; p += (size_t)8388608 * 2;   // x bf16 [8192][1024]
    ushort* wqb = (ushort*)p; p += (size_t)3145728 * 2;   // Wqkv bf16 [3072][1024]
    ushort* wob = (ushort*)p; p += (size_t)1048576 * 2;   // Wo bf16 [1024][1024]
    ushort* qo  = (ushort*)p; p += (size_t)8388608 * 2;   // Q bf16 [bh][s][64] (pre-scaled)
    ushort* ko  = (ushort*)p; p += (size_t)8388608 * 2;   // K bf16 [bh][s][64]
    ushort* vto = (ushort*)p; p += (size_t)8388608 * 2;   // V^T bf16 [bh][64][s]
    ushort* ctx = (ushort*)p; p += (size_t)8388608 * 2;   // ctx bf16 [8192][1024]
    uint32_t* mb = (uint32_t*)p;                          // packed mask bits (kt-major), 2 MB

    cvt_bf16<<<8192, 256, 0, stream>>>(x, xb, 2097152);
    cvt_bf16<<<3072, 256, 0, stream>>>(Wqkv, wqb, 786432);
    cvt_bf16<<<1024, 256, 0, stream>>>(Wo, wob, 262144);
    pack_mask<<<65536, 256, 0, stream>>>(mask, mb);
    qkv_gemm<<<1536, 256, 0, stream>>>(xb, wqb, bqkv, qo, ko, vto);
    attn_kernel<<<1024, 256, 0, stream>>>(qo, ko, vto, mb, ctx);
    out_gemm<<<512, 256, 0, stream>>>(ctx, wob, bo, out);
}

// Round 5
// 405.110 us; speedup vs baseline: 1.6307x; 1.0331x over previous
//
#include <hip/hip_runtime.h>
#include <stdint.h>

// Problem constants
#define B_ 4
#define S_ 2048
#define E_ 1024
#define H_ 16
#define HD_ 64

typedef __attribute__((ext_vector_type(8))) short bf16x8;   // 8 bf16 = 4 VGPRs (MFMA A/B frag)
typedef __attribute__((ext_vector_type(4))) float f32x4;    // MFMA C/D frag

__device__ __forceinline__ ushort f2b(float f) {
    union { float f; uint32_t u; } c; c.f = f;
    return (ushort)((c.u + 0x8000u) >> 16);   // round-to-nearest (ties up)
}

// async global->LDS, 16B per lane; LDS dest = wave-uniform base + lane*16
__device__ __forceinline__ void gl2lds16(const ushort* g, const ushort* l) {
    __builtin_amdgcn_global_load_lds(
        (const __attribute__((address_space(1))) unsigned int*)g,
        (__attribute__((address_space(3))) unsigned int*)l,
        16, 0, 0);
}
__device__ __forceinline__ void gl2lds16raw(const void* g, const void* l) {
    __builtin_amdgcn_global_load_lds(
        (const __attribute__((address_space(1))) unsigned int*)g,
        (__attribute__((address_space(3))) unsigned int*)l,
        16, 0, 0);
}

// ---------------------------------------------------------------- converts
__global__ __launch_bounds__(256) void cvt_bf16(const float* __restrict__ src,
                                                ushort* __restrict__ dst, int n4) {
    int i = blockIdx.x * 256 + threadIdx.x;
    if (i < n4) {
        float4 f = ((const float4*)src)[i];
        ushort4 o;
        o.x = f2b(f.x); o.y = f2b(f.y); o.z = f2b(f.z); o.w = f2b(f.w);
        ((ushort4*)dst)[i] = o;
    }
}

// mask [B,S,S] int32 (0/1) -> bit-packed, kt-major:
// mb[((b*32 + kt)*2048 + q)*2 + w] bit c = mask[b][q][kt*64 + w*32 + c]
__global__ __launch_bounds__(256) void pack_mask(const int* __restrict__ mask,
                                                 uint32_t* __restrict__ mb) {
    int i = blockIdx.x * 256 + threadIdx.x;   // 16777216 threads
    unsigned long long bal = __ballot(mask[i] == 1);
    int lane = threadIdx.x & 63;
    if (lane < 2) {
        int b = i >> 22, q = (i >> 11) & 2047, c = i & 2047;
        int kt = c >> 6;
        mb[((uint64_t)(b * 32 + kt) * 2048 + q) * 2 + lane] =
            (lane == 0) ? (uint32_t)bal : (uint32_t)(bal >> 32);
    }
}

// ---------------------------------------------------------------- GEMM core
template <int KD>
__device__ __forceinline__ void gemm_bt_core(
    const ushort* __restrict__ A, const ushort* __restrict__ Bm,
    int m0, int n0, ushort* As, ushort* Bs, f32x4 (&acc)[4][4])
{
    const int tid  = threadIdx.x;
    const int lane = tid & 63;
    const int wave = tid >> 6;
    const int wm = wave >> 1, wn = wave & 1;
    const int fr = lane & 15;
    const int fk = (lane >> 4) * 8;
    const int lrow = lane >> 2;
    const int lk   = (lane & 3) * 8;

    const f32x4 fz = {0.f, 0.f, 0.f, 0.f};
#pragma unroll
    for (int i = 0; i < 4; ++i)
#pragma unroll
        for (int j = 0; j < 4; ++j) acc[i][j] = fz;

    for (int kt = 0; kt < KD / 32; ++kt) {
        const int k0 = kt * 32;
        __syncthreads();
#pragma unroll
        for (int t = 0; t < 2; ++t) {
            const int r0 = t * 64 + wave * 16;
            gl2lds16(&A [(uint64_t)(m0 + r0 + lrow) * KD + k0 + lk], &As[r0 * 32]);
            gl2lds16(&Bm[(uint64_t)(n0 + r0 + lrow) * KD + k0 + lk], &Bs[r0 * 32]);
        }
        __syncthreads();
        bf16x8 af[4], bfr[4];
#pragma unroll
        for (int i = 0; i < 4; ++i)
            af[i] = *(const bf16x8*)&As[(wm * 64 + i * 16 + fr) * 32 + fk];
#pragma unroll
        for (int j = 0; j < 4; ++j)
            bfr[j] = *(const bf16x8*)&Bs[(wn * 64 + j * 16 + fr) * 32 + fk];
#pragma unroll
        for (int i = 0; i < 4; ++i)
#pragma unroll
            for (int j = 0; j < 4; ++j)
                acc[i][j] = __builtin_amdgcn_mfma_f32_16x16x32_bf16(af[i], bfr[j], acc[i][j], 0, 0, 0);
    }
}

// ---------------------------------------------------------------- QKV GEMM
__global__ __launch_bounds__(256) void qkv_gemm(
    const ushort* __restrict__ xb, const ushort* __restrict__ wb,
    const float* __restrict__ bqkv,
    ushort* __restrict__ qo, ushort* __restrict__ ko, ushort* __restrict__ vto)
{
    __shared__ ushort As[128 * 32];
    __shared__ ushort Bs[128 * 32];
    f32x4 acc[4][4];
    const int i = blockIdx.x;
    const int c = i & 7, t = i >> 3;          // t in [0,192)
    const int n0 = (c + 8 * (t % 3)) * 128;   // 24 N-tiles
    const int m0 = (t / 3) * 128;             // 64 M-tiles
    gemm_bt_core<1024>(xb, wb, m0, n0, As, Bs, acc);

    const int lane = threadIdx.x & 63, wave = threadIdx.x >> 6;
    const int wm = wave >> 1, wn = wave & 1;
    const int col = lane & 15, rg = lane >> 4;
#pragma unroll
    for (int j = 0; j < 4; ++j) {
        const int n = n0 + wn * 64 + j * 16 + col;
        const int h = n / 192, f = n % 192;
        const float bias = bqkv[n];
#pragma unroll
        for (int i2 = 0; i2 < 4; ++i2) {
            const int mbase = m0 + wm * 64 + i2 * 16 + rg * 4;
            if (f < 128) {
#pragma unroll
                for (int v = 0; v < 4; ++v) {
                    const int m = mbase + v;
                    const int b = m >> 11, s = m & 2047;
                    const float val = acc[i2][j][v] + bias;
                    if (f < 64) qo[((uint64_t)(b * 16 + h) * 2048 + s) * 64 + f]        = f2b(val * 0.125f);
                    else        ko[((uint64_t)(b * 16 + h) * 2048 + s) * 64 + (f - 64)] = f2b(val);
                }
            } else {
                const int b = mbase >> 11, s = mbase & 2047;
                ushort4 pk;
                pk.x = f2b(acc[i2][j][0] + bias);
                pk.y = f2b(acc[i2][j][1] + bias);
                pk.z = f2b(acc[i2][j][2] + bias);
                pk.w = f2b(acc[i2][j][3] + bias);
                *(ushort4*)&vto[((uint64_t)(b * 16 + h) * 64 + (f - 128)) * 2048 + s] = pk;
            }
        }
    }
}

// ---------------------------------------------------------------- flash attention v5
// v4 substrate (single-barrier K/V/mask LDS double-buffer) + S^T score layout:
// QK MFMA operands swapped so D col=q, row=k -> each lane holds 4 consecutive k
// for one q. P writes become 8 ds_write_b64 (was 32 ds_write_b16, 8-way conflicts),
// mask reads become 16-lane broadcasts, l-sum is per-lane scalar (2 shuffles total).
__global__ __launch_bounds__(256, 3) void attn_kernel(
    const ushort* __restrict__ qa, const ushort* __restrict__ ka,
    const ushort* __restrict__ vta, const uint32_t* __restrict__ mbits,
    ushort* __restrict__ ctxo)
{
    __shared__ __align__(16) ushort SMEM[128 * 64];    // 16 KB: Q stage / per-wave P / ctx stage
    __shared__ __align__(16) ushort Ks[2][64 * 64];    // 16 KB double-buffered K
    __shared__ __align__(16) ushort Vts[2][64 * 64];   // 16 KB double-buffered V^T [d][k]
    __shared__ __align__(16) uint32_t Ms[2][256];      // 2 KB mask bits, double-buffered

    const int bid = blockIdx.x;
    const int qb = bid & 15;                  // natural order: same-bh blocks adjacent
    const int bh = bid >> 4;
    const int b = bh >> 4;
    const int tid = threadIdx.x, lane = tid & 63, wave = tid >> 6;
    const int col = lane & 15, rg = lane >> 4;

    const uint64_t bhoff = (uint64_t)bh * (S_ * 64);
    const ushort* qp = qa + bhoff + (uint64_t)qb * 128 * 64;
    const ushort* kp = ka + bhoff;
    const ushort* vp = vta + bhoff;                       // [64][2048]
    const uint32_t* mkb = mbits + ((uint64_t)(b * 32) * 2048 + qb * 128) * 2;  // +kt*4096

    // stage Q tile (each wave its own 4 KB slice)
#pragma unroll
    for (int t4 = 0; t4 < 4; ++t4) {
        const int o = (wave * 4 + t4) * 512;
        gl2lds16(&qp[o + lane * 8], &SMEM[o]);
    }
    // prefetch kt=0 K/V/mask into buffer 0
#pragma unroll
    for (int t = 0; t < 2; ++t) {
        const int o = (wave * 2 + t) * 512;
        gl2lds16(&kp[o + lane * 8], &Ks[0][o]);
        const int r0 = (wave * 2 + t) * 8;
        gl2lds16(&vp[(uint64_t)(r0 + (lane >> 3)) * S_ + (lane & 7) * 8], &Vts[0][r0 * 64]);
    }
    if (wave == 0) gl2lds16raw(mkb + lane * 4, &Ms[0][0]);
    __syncthreads();

    bf16x8 aq[2][2];                      // Q fragments (B-operand now; same read pattern)
#pragma unroll
    for (int i = 0; i < 2; ++i)
#pragma unroll
        for (int k2 = 0; k2 < 2; ++k2)
            aq[i][k2] = *(const bf16x8*)&SMEM[(wave * 32 + i * 16 + col) * 64 + k2 * 32 + rg * 8];

    const f32x4 fz = {0.f, 0.f, 0.f, 0.f};
    f32x4 acc[4][2];                      // ctx^T: row=d, col=q (q = wave*32 + i*16 + col)
#pragma unroll
    for (int dt = 0; dt < 4; ++dt)
#pragma unroll
        for (int i = 0; i < 2; ++i) acc[dt][i] = fz;
    float lsum[2] = {0.f, 0.f};           // per-lane partial row sum for q = wave*32+i*16+col

    ushort* Ps = &SMEM[wave * 2048];      // wave-private 32x64 P[q][k], 16B-unit XOR swizzle

    for (int kt = 0; kt < 32; ++kt) {
        const int buf = kt & 1;
        // issue prefetch for kt+1 into the other buffer (lands during this phase)
        if (kt < 31) {
            const uint64_t knext = (uint64_t)(kt + 1) * 4096;
#pragma unroll
            for (int t = 0; t < 2; ++t) {
                const int o = (wave * 2 + t) * 512;
                gl2lds16(&kp[knext + o + lane * 8], &Ks[buf ^ 1][o]);
                const int r0 = (wave * 2 + t) * 8;
                gl2lds16(&vp[(uint64_t)(r0 + (lane >> 3)) * S_ + (kt + 1) * 64 + (lane & 7) * 8],
                         &Vts[buf ^ 1][r0 * 64]);
            }
            if (wave == 0) gl2lds16raw(mkb + (uint64_t)(kt + 1) * 4096 + lane * 4,
                                       &Ms[buf ^ 1][0]);
        }

        // scores S^T: sc[i][j], D col = q-local (col), D row = k-local (rg*4+v)
        f32x4 sc[2][4];
#pragma unroll
        for (int j = 0; j < 4; ++j) {
            bf16x8 bk0 = *(const bf16x8*)&Ks[buf][(j * 16 + col) * 64 + rg * 8];
            bf16x8 bk1 = *(const bf16x8*)&Ks[buf][(j * 16 + col) * 64 + 32 + rg * 8];
#pragma unroll
            for (int i = 0; i < 2; ++i) {
                f32x4 z = __builtin_amdgcn_mfma_f32_16x16x32_bf16(bk0, aq[i][0], fz, 0, 0, 0);
                sc[i][j] = __builtin_amdgcn_mfma_f32_16x16x32_bf16(bk1, aq[i][1], z, 0, 0, 0);
            }
        }

        // mask + exp (fixed m=0), packed b64 P stores, per-lane partial sums
#pragma unroll
        for (int i = 0; i < 2; ++i) {
            const int qrow = i * 16 + col;                        // wave-local q row
            const uint2 mw = *(const uint2*)&Ms[buf][(wave * 32 + qrow) * 2];  // broadcast
            float ts = 0.f;
#pragma unroll
            for (int j = 0; j < 4; ++j) {
                const uint32_t w = (j & 2) ? mw.y : mw.x;
                const int base = (j & 1) * 16 + rg * 4;           // bit index of k = j*16+rg*4
                ushort4 pk;
                {
                    const float s0 = ((w >> (base + 0)) & 1u) ? 0.f : sc[i][j][0];
                    const float s1 = ((w >> (base + 1)) & 1u) ? 0.f : sc[i][j][1];
                    const float s2 = ((w >> (base + 2)) & 1u) ? 0.f : sc[i][j][2];
                    const float s3 = ((w >> (base + 3)) & 1u) ? 0.f : sc[i][j][3];
                    const float p0 = __expf(s0), p1 = __expf(s1);
                    const float p2 = __expf(s2), p3 = __expf(s3);
                    ts += (p0 + p1) + (p2 + p3);
                    pk.x = f2b(p0); pk.y = f2b(p1); pk.z = f2b(p2); pk.w = f2b(p3);
                }
                // k = j*16 + rg*4 + v; 16B unit u = j*2 + (rg>>1), swizzle u^(q&7)
                const int u = ((j * 2 + (rg >> 1)) ^ (col & 7));
                *(ushort4*)&Ps[qrow * 64 + u * 8 + (rg & 1) * 4] = pk;
            }
            lsum[i] += ts;
        }

        // PV: acc[d][q] += Vt[d][k] * P[q][k]  (P as B-operand: row q, 8 consecutive k)
        bf16x8 bp[2][2];
#pragma unroll
        for (int i = 0; i < 2; ++i)
#pragma unroll
            for (int k2 = 0; k2 < 2; ++k2)
                bp[i][k2] = *(const bf16x8*)&Ps[(i * 16 + col) * 64 + (((k2 * 4 + rg) ^ (col & 7)) << 3)];
#pragma unroll
        for (int dt = 0; dt < 4; ++dt) {
            bf16x8 av0 = *(const bf16x8*)&Vts[buf][(dt * 16 + col) * 64 + rg * 8];
            bf16x8 av1 = *(const bf16x8*)&Vts[buf][(dt * 16 + col) * 64 + 32 + rg * 8];
#pragma unroll
            for (int i = 0; i < 2; ++i) {
                acc[dt][i] = __builtin_amdgcn_mfma_f32_16x16x32_bf16(av0, bp[i][0], acc[dt][i], 0, 0, 0);
                acc[dt][i] = __builtin_amdgcn_mfma_f32_16x16x32_bf16(av1, bp[i][1], acc[dt][i], 0, 0, 0);
            }
        }
        __syncthreads();   // single barrier: drains kt+1 prefetch (full phase old) + LDS reads
    }

    // row sums live per-lane split across rg groups: reduce over lanes 16/32 apart.
    float linv[2];
#pragma unroll
    for (int i = 0; i < 2; ++i) {
        float ts = lsum[i];
        ts += __shfl_xor(ts, 16);
        ts += __shfl_xor(ts, 32);
        linv[i] = 1.0f / ts;              // lane's q = wave*32+i*16+col == acc col ✓
    }

    // transpose ctx^T back through SMEM (swizzled) for coalesced global store
#pragma unroll
    for (int dt = 0; dt < 4; ++dt)
#pragma unroll
        for (int i = 0; i < 2; ++i) {
            const int q = wave * 32 + i * 16 + col;
            const int d = dt * 16 + rg * 4;
            const int gg = (d >> 3) ^ (q & 7);
            ushort4 pk;
            pk.x = f2b(acc[dt][i][0] * linv[i]);
            pk.y = f2b(acc[dt][i][1] * linv[i]);
            pk.z = f2b(acc[dt][i][2] * linv[i]);
            pk.w = f2b(acc[dt][i][3] * linv[i]);
            *(ushort4*)&SMEM[q * 64 + gg * 8 + (d & 7)] = pk;
        }
    __syncthreads();
    const int h = bh & 15;
    const uint64_t obase = (uint64_t)(b * S_ + qb * 128) * E_ + (uint64_t)h * 64;
#pragma unroll
    for (int t4 = 0; t4 < 4; ++t4) {
        const int id = tid + t4 * 256;
        const int r = id >> 3, c8 = id & 7;
        *(bf16x8*)&ctxo[obase + (uint64_t)r * E_ + c8 * 8] =
            *(const bf16x8*)&SMEM[r * 64 + ((c8 ^ (r & 7)) << 3)];
    }
}

// ---------------------------------------------------------------- output GEMM
__global__ __launch_bounds__(256) void out_gemm(
    const ushort* __restrict__ ctxb, const ushort* __restrict__ wob,
    const float* __restrict__ bo, float* __restrict__ out)
{
    __shared__ ushort As[128 * 32];
    __shared__ ushort Bs[128 * 32];
    f32x4 acc[4][4];
    const int i = blockIdx.x;
    const int n0 = (i & 7) * 128;             // 8 N-tiles
    const int m0 = (i >> 3) * 128;            // 64 M-tiles
    gemm_bt_core<1024>(ctxb, wob, m0, n0, As, Bs, acc);

    const int lane = threadIdx.x & 63, wave = threadIdx.x >> 6;
    const int wm = wave >> 1, wn = wave & 1;
    const int col = lane & 15, rg = lane >> 4;
#pragma unroll
    for (int j = 0; j < 4; ++j) {
        const int n = n0 + wn * 64 + j * 16 + col;
        const float bias = bo[n];
#pragma unroll
        for (int i2 = 0; i2 < 4; ++i2) {
            const int mb2 = m0 + wm * 64 + i2 * 16 + rg * 4;
#pragma unroll
            for (int v = 0; v < 4; ++v)
                out[(uint64_t)(mb2 + v) * 1024 + n] = acc[i2][j][v] + bias;
        }
    }
}

// ---------------------------------------------------------------- launch
extern "C" void kernel_launch(void* const* d_in, const int* in_sizes, int n_in,
                              void* d_out, int out_size, void* d_ws, size_t ws_size,
                              hipStream_t stream)
{
    const float* x    = (const float*)d_in[0];
    const int*   mask = (const int*)d_in[1];
    const float* Wqkv = (const float*)d_in[2];
    const float* bqkv = (const float*)d_in[3];
    const float* Wo   = (const float*)d_in[4];
    const float* bo   = (const float*)d_in[5];
    float* out = (float*)d_out;

    char* p = (char*)d_ws;
    ushort* xb  = (ushort*)p; p += (size_t)8388608 * 2;   // x bf16 [8192][1024]
    ushort* wqb = (ushort*)p; p += (size_t)3145728 * 2;   // Wqkv bf16 [3072][1024]
    ushort* wob = (ushort*)p; p += (size_t)1048576 * 2;   // Wo bf16 [1024][1024]
    ushort* qo  = (ushort*)p; p += (size_t)8388608 * 2;   // Q bf16 [bh][s][64] (pre-scaled)
    ushort* ko  = (ushort*)p; p += (size_t)8388608 * 2;   // K bf16 [bh][s][64]
    ushort* vto = (ushort*)p; p += (size_t)8388608 * 2;   // V^T bf16 [bh][64][s]
    ushort* ctx = (ushort*)p; p += (size_t)8388608 * 2;   // ctx bf16 [8192][1024]
    uint32_t* mb = (uint32_t*)p;                          // packed mask bits (kt-major), 2 MB

    cvt_bf16<<<8192, 256, 0, stream>>>(x, xb, 2097152);
    cvt_bf16<<<3072, 256, 0, stream>>>(Wqkv, wqb, 786432);
    cvt_bf16<<<1024, 256, 0, stream>>>(Wo, wob, 262144);
    pack_mask<<<65536, 256, 0, stream>>>(mask, mb);
    qkv_gemm<<<1536, 256, 0, stream>>>(xb, wqb, bqkv, qo, ko, vto);
    attn_kernel<<<1024, 256, 0, stream>>>(qo, ko, vto, mb, ctx);
    out_gemm<<<512, 256, 0, stream>>>(ctx, wob, bo, out);
}

// Round 6
// 378.524 us; speedup vs baseline: 1.7452x; 1.0702x over previous
//
#include <hip/hip_runtime.h>
#include <stdint.h>

// Problem constants
#define B_ 4
#define S_ 2048
#define E_ 1024
#define H_ 16
#define HD_ 64

typedef __attribute__((ext_vector_type(8))) short bf16x8;   // 8 bf16 = 4 VGPRs (MFMA A/B frag)
typedef __attribute__((ext_vector_type(4))) float f32x4;    // MFMA C/D frag

__device__ __forceinline__ ushort f2b(float f) {
    union { float f; uint32_t u; } c; c.f = f;
    return (ushort)((c.u + 0x8000u) >> 16);   // round-to-nearest (ties up)
}

// async global->LDS, 16B per lane; LDS dest = wave-uniform base + lane*16,
// global src = PER-LANE address (gather) -> source-side permutations are free.
__device__ __forceinline__ void gl2lds16(const ushort* g, const ushort* l) {
    __builtin_amdgcn_global_load_lds(
        (const __attribute__((address_space(1))) unsigned int*)g,
        (__attribute__((address_space(3))) unsigned int*)l,
        16, 0, 0);
}
__device__ __forceinline__ void gl2lds16raw(const void* g, const void* l) {
    __builtin_amdgcn_global_load_lds(
        (const __attribute__((address_space(1))) unsigned int*)g,
        (__attribute__((address_space(3))) unsigned int*)l,
        16, 0, 0);
}

// ---------------------------------------------------------------- converts
__global__ __launch_bounds__(256) void cvt_bf16(const float* __restrict__ src,
                                                ushort* __restrict__ dst, int n4) {
    int i = blockIdx.x * 256 + threadIdx.x;
    if (i < n4) {
        float4 f = ((const float4*)src)[i];
        ushort4 o;
        o.x = f2b(f.x); o.y = f2b(f.y); o.z = f2b(f.z); o.w = f2b(f.w);
        ((ushort4*)dst)[i] = o;
    }
}

// mask [B,S,S] int32 (0/1) -> bit-packed, kt-major:
// mb[((b*32 + kt)*2048 + q)*2 + w] bit c = mask[b][q][kt*64 + w*32 + c]
__global__ __launch_bounds__(256) void pack_mask(const int* __restrict__ mask,
                                                 uint32_t* __restrict__ mb) {
    int i = blockIdx.x * 256 + threadIdx.x;   // 16777216 threads
    unsigned long long bal = __ballot(mask[i] == 1);
    int lane = threadIdx.x & 63;
    if (lane < 2) {
        int b = i >> 22, q = (i >> 11) & 2047, c = i & 2047;
        int kt = c >> 6;
        mb[((uint64_t)(b * 32 + kt) * 2048 + q) * 2 + lane] =
            (lane == 0) ? (uint32_t)bal : (uint32_t)(bal >> 32);
    }
}

// ---------------------------------------------------------------- GEMM core
template <int KD>
__device__ __forceinline__ void gemm_bt_core(
    const ushort* __restrict__ A, const ushort* __restrict__ Bm,
    int m0, int n0, ushort* As, ushort* Bs, f32x4 (&acc)[4][4])
{
    const int tid  = threadIdx.x;
    const int lane = tid & 63;
    const int wave = tid >> 6;
    const int wm = wave >> 1, wn = wave & 1;
    const int fr = lane & 15;
    const int fk = (lane >> 4) * 8;
    const int lrow = lane >> 2;
    const int lk   = (lane & 3) * 8;

    const f32x4 fz = {0.f, 0.f, 0.f, 0.f};
#pragma unroll
    for (int i = 0; i < 4; ++i)
#pragma unroll
        for (int j = 0; j < 4; ++j) acc[i][j] = fz;

    for (int kt = 0; kt < KD / 32; ++kt) {
        const int k0 = kt * 32;
        __syncthreads();
#pragma unroll
        for (int t = 0; t < 2; ++t) {
            const int r0 = t * 64 + wave * 16;
            gl2lds16(&A [(uint64_t)(m0 + r0 + lrow) * KD + k0 + lk], &As[r0 * 32]);
            gl2lds16(&Bm[(uint64_t)(n0 + r0 + lrow) * KD + k0 + lk], &Bs[r0 * 32]);
        }
        __syncthreads();
        bf16x8 af[4], bfr[4];
#pragma unroll
        for (int i = 0; i < 4; ++i)
            af[i] = *(const bf16x8*)&As[(wm * 64 + i * 16 + fr) * 32 + fk];
#pragma unroll
        for (int j = 0; j < 4; ++j)
            bfr[j] = *(const bf16x8*)&Bs[(wn * 64 + j * 16 + fr) * 32 + fk];
#pragma unroll
        for (int i = 0; i < 4; ++i)
#pragma unroll
            for (int j = 0; j < 4; ++j)
                acc[i][j] = __builtin_amdgcn_mfma_f32_16x16x32_bf16(af[i], bfr[j], acc[i][j], 0, 0, 0);
    }
}

// ---------------------------------------------------------------- QKV GEMM
// r1-proven 2D grid: consecutive blocks share the B(weight)-tile in L2.
__global__ __launch_bounds__(256) void qkv_gemm(
    const ushort* __restrict__ xb, const ushort* __restrict__ wb,
    const float* __restrict__ bqkv,
    ushort* __restrict__ qo, ushort* __restrict__ ko, ushort* __restrict__ vto)
{
    __shared__ ushort As[128 * 32];
    __shared__ ushort Bs[128 * 32];
    f32x4 acc[4][4];
    const int m0 = blockIdx.x * 128;
    const int n0 = blockIdx.y * 128;
    gemm_bt_core<1024>(xb, wb, m0, n0, As, Bs, acc);

    const int lane = threadIdx.x & 63, wave = threadIdx.x >> 6;
    const int wm = wave >> 1, wn = wave & 1;
    const int col = lane & 15, rg = lane >> 4;
#pragma unroll
    for (int j = 0; j < 4; ++j) {
        const int n = n0 + wn * 64 + j * 16 + col;
        const int h = n / 192, f = n % 192;
        const float bias = bqkv[n];
#pragma unroll
        for (int i2 = 0; i2 < 4; ++i2) {
            const int mbase = m0 + wm * 64 + i2 * 16 + rg * 4;
            if (f < 128) {
#pragma unroll
                for (int v = 0; v < 4; ++v) {
                    const int m = mbase + v;
                    const int b = m >> 11, s = m & 2047;
                    const float val = acc[i2][j][v] + bias;
                    if (f < 64) qo[((uint64_t)(b * 16 + h) * 2048 + s) * 64 + f]        = f2b(val * 0.125f);
                    else        ko[((uint64_t)(b * 16 + h) * 2048 + s) * 64 + (f - 64)] = f2b(val);
                }
            } else {
                const int b = mbase >> 11, s = mbase & 2047;
                ushort4 pk;
                pk.x = f2b(acc[i2][j][0] + bias);
                pk.y = f2b(acc[i2][j][1] + bias);
                pk.z = f2b(acc[i2][j][2] + bias);
                pk.w = f2b(acc[i2][j][3] + bias);
                *(ushort4*)&vto[((uint64_t)(b * 16 + h) * 64 + (f - 128)) * 2048 + s] = pk;
            }
        }
    }
}

// ---------------------------------------------------------------- flash attention v6
// P never touches LDS: K rows staged permuted by sigma (k2,jj,rg,v)->(k2,rg,jj,v),
// so after the S^T MFMA each lane holds exactly the consecutive-k values the PV
// B-operand fragment needs -> bp packed from sc registers. K/V staged with a
// source-side 16B-unit XOR swizzle (unit ^= row&7) so all fragment b128 reads
// spread over all 32 banks (8 dwords/bank = structural minimum).
__global__ __launch_bounds__(256, 3) void attn_kernel(
    const ushort* __restrict__ qa, const ushort* __restrict__ ka,
    const ushort* __restrict__ vta, const uint32_t* __restrict__ mbits,
    ushort* __restrict__ ctxo)
{
    __shared__ __align__(16) ushort SMEM[128 * 64];    // 16 KB: Q stage / ctx stage
    __shared__ __align__(16) ushort Ks[2][64 * 64];    // 16 KB dbuf K (sigma rows, swizzled units)
    __shared__ __align__(16) ushort Vts[2][64 * 64];   // 16 KB dbuf V^T [d][k] (swizzled units)
    __shared__ __align__(16) uint32_t Ms[2][256];      // 2 KB mask bits, dbuf

    const int bid = blockIdx.x;
    const int qb = bid & 15;                  // natural order: same-bh blocks adjacent
    const int bh = bid >> 4;
    const int b = bh >> 4;
    const int tid = threadIdx.x, lane = tid & 63, wave = tid >> 6;
    const int col = lane & 15, rg = lane >> 4;

    const uint64_t bhoff = (uint64_t)bh * (S_ * 64);
    const ushort* qp = qa + bhoff + (uint64_t)qb * 128 * 64;
    const ushort* kp = ka + bhoff;
    const ushort* vp = vta + bhoff;                       // [64][2048]
    const uint32_t* mkb = mbits + ((uint64_t)(b * 32) * 2048 + qb * 128) * 2;  // +kt*4096

    // staging geometry: 8 LDS rows / instruction; per-lane source gather
    const int lr = lane >> 3;                 // row within 8-row group (= r&7)
    const int usw = (lane & 7) ^ lr;          // XOR-swizzled 16B unit
    const int r0s = wave * 16 + lr;           // t=0 LDS row (wave*2+0)*8 + lr
    const int r1s = r0s + 8;                  // t=1 LDS row
    // sigma(r): bits (k2,jj,rg,v) -> (k2,rg,jj,v)
    const int sg0 = (r0s & 32) | ((r0s & 12) << 1) | ((r0s & 16) >> 2) | (r0s & 3);
    const int sg1 = (r1s & 32) | ((r1s & 12) << 1) | ((r1s & 16) >> 2) | (r1s & 3);
    const int kb0 = sg0 * 64 + usw * 8;       // K source offsets (element units)
    const int kb1 = sg1 * 64 + usw * 8;
    const int vb0 = r0s * 2048 + usw * 8;     // V source offsets (rows natural)
    const int vb1 = r1s * 2048 + usw * 8;
    const int ldst0 = wave * 1024;            // LDS dst (elements): (wave*2+0)*512
    const int ldst1 = ldst0 + 512;

    // stage Q tile (natural layout; read once into registers)
#pragma unroll
    for (int t4 = 0; t4 < 4; ++t4) {
        const int o = (wave * 4 + t4) * 512;
        gl2lds16(&qp[o + lane * 8], &SMEM[o]);
    }
    // prefetch kt=0 K/V/mask into buffer 0
    gl2lds16(&kp[kb0], &Ks[0][ldst0]);
    gl2lds16(&kp[kb1], &Ks[0][ldst1]);
    gl2lds16(&vp[vb0], &Vts[0][ldst0]);
    gl2lds16(&vp[vb1], &Vts[0][ldst1]);
    if (wave == 0) gl2lds16raw(mkb + lane * 4, &Ms[0][0]);
    __syncthreads();

    bf16x8 aq[2][2];                      // Q fragments (natural k order)
#pragma unroll
    for (int i = 0; i < 2; ++i)
#pragma unroll
        for (int k2 = 0; k2 < 2; ++k2)
            aq[i][k2] = *(const bf16x8*)&SMEM[(wave * 32 + i * 16 + col) * 64 + k2 * 32 + rg * 8];

    const f32x4 fz = {0.f, 0.f, 0.f, 0.f};
    f32x4 acc[4][2];                      // ctx^T: row=d, col=q (q = wave*32 + i*16 + col)
#pragma unroll
    for (int dt = 0; dt < 4; ++dt)
#pragma unroll
        for (int i = 0; i < 2; ++i) acc[dt][i] = fz;
    float lsum[2] = {0.f, 0.f};

    const int u0 = (rg ^ (col & 7)) << 3; // fragment read offset for k-units rg (global k 0..31)
    // second half (global k 32..63) = u0 ^ 32

    for (int kt = 0; kt < 32; ++kt) {
        const int buf = kt & 1;
        // issue prefetch for kt+1 into the other buffer (lands during this phase)
        if (kt < 31) {
            const int knext = (kt + 1) * 4096;
            gl2lds16(&kp[knext + kb0], &Ks[buf ^ 1][ldst0]);
            gl2lds16(&kp[knext + kb1], &Ks[buf ^ 1][ldst1]);
            gl2lds16(&vp[vb0 + (kt + 1) * 64], &Vts[buf ^ 1][ldst0]);
            gl2lds16(&vp[vb1 + (kt + 1) * 64], &Vts[buf ^ 1][ldst1]);
            if (wave == 0) gl2lds16raw(mkb + (uint64_t)(kt + 1) * 4096 + lane * 4,
                                       &Ms[buf ^ 1][0]);
        }

        // scores S^T vs sigma-permuted keys: sc[i][j][v] = S[key sg(j*16+rg*4+v)][q=col]
        f32x4 sc[2][4];
#pragma unroll
        for (int j = 0; j < 4; ++j) {
            bf16x8 bk0 = *(const bf16x8*)&Ks[buf][(j * 16 + col) * 64 + u0];
            bf16x8 bk1 = *(const bf16x8*)&Ks[buf][(j * 16 + col) * 64 + (u0 ^ 32)];
#pragma unroll
            for (int i = 0; i < 2; ++i) {
                f32x4 z = __builtin_amdgcn_mfma_f32_16x16x32_bf16(bk0, aq[i][0], fz, 0, 0, 0);
                sc[i][j] = __builtin_amdgcn_mfma_f32_16x16x32_bf16(bk1, aq[i][1], z, 0, 0, 0);
            }
        }

        // mask + exp (fixed m=0); pack P directly into PV B-fragments (registers only).
        // key held = (j&2)*16 + rg*8 + (j&1)*4 + v -> mask word j&2, bit rg*8+(j&1)*4+v.
        bf16x8 bp[2][2];
#pragma unroll
        for (int i = 0; i < 2; ++i) {
            const uint2 mw = *(const uint2*)&Ms[buf][(wave * 32 + i * 16 + col) * 2];
            float ts = 0.f;
            union { ushort u[8]; bf16x8 v; } p0, p1;
#pragma unroll
            for (int j = 0; j < 4; ++j) {
                const uint32_t w = (j & 2) ? mw.y : mw.x;
                const int sb = rg * 8 + (j & 1) * 4;
#pragma unroll
                for (int v = 0; v < 4; ++v) {
                    const float s = ((w >> (sb + v)) & 1u) ? 0.f : sc[i][j][v];
                    const float pe = __expf(s);
                    ts += pe;
                    const ushort pb = f2b(pe);
                    if (j < 2) p0.u[(j & 1) * 4 + v] = pb;
                    else       p1.u[(j & 1) * 4 + v] = pb;
                }
            }
            bp[i][0] = p0.v;
            bp[i][1] = p1.v;
            lsum[i] += ts;
        }

        // PV: acc[d][q] += Vt[d][k] * P[q][k]; V rows natural, fragments from registers
#pragma unroll
        for (int dt = 0; dt < 4; ++dt) {
            bf16x8 av0 = *(const bf16x8*)&Vts[buf][(dt * 16 + col) * 64 + u0];
            bf16x8 av1 = *(const bf16x8*)&Vts[buf][(dt * 16 + col) * 64 + (u0 ^ 32)];
#pragma unroll
            for (int i = 0; i < 2; ++i) {
                acc[dt][i] = __builtin_amdgcn_mfma_f32_16x16x32_bf16(av0, bp[i][0], acc[dt][i], 0, 0, 0);
                acc[dt][i] = __builtin_amdgcn_mfma_f32_16x16x32_bf16(av1, bp[i][1], acc[dt][i], 0, 0, 0);
            }
        }
        __syncthreads();   // single barrier: drains kt+1 prefetch (full phase old) + LDS reads
    }

    // reduce row sums across rg groups (lanes 16/32 apart), 1/l per q=col lane
    float linv[2];
#pragma unroll
    for (int i = 0; i < 2; ++i) {
        float ts = lsum[i];
        ts += __shfl_xor(ts, 16);
        ts += __shfl_xor(ts, 32);
        linv[i] = 1.0f / ts;
    }

    // transpose ctx^T back through SMEM (swizzled) for coalesced global store
#pragma unroll
    for (int dt = 0; dt < 4; ++dt)
#pragma unroll
        for (int i = 0; i < 2; ++i) {
            const int q = wave * 32 + i * 16 + col;
            const int d = dt * 16 + rg * 4;
            const int gg = (d >> 3) ^ (q & 7);
            ushort4 pk;
            pk.x = f2b(acc[dt][i][0] * linv[i]);
            pk.y = f2b(acc[dt][i][1] * linv[i]);
            pk.z = f2b(acc[dt][i][2] * linv[i]);
            pk.w = f2b(acc[dt][i][3] * linv[i]);
            *(ushort4*)&SMEM[q * 64 + gg * 8 + (d & 7)] = pk;
        }
    __syncthreads();
    const int h = bh & 15;
    const uint64_t obase = (uint64_t)(b * S_ + qb * 128) * E_ + (uint64_t)h * 64;
#pragma unroll
    for (int t4 = 0; t4 < 4; ++t4) {
        const int id = tid + t4 * 256;
        const int r = id >> 3, c8 = id & 7;
        *(bf16x8*)&ctxo[obase + (uint64_t)r * E_ + c8 * 8] =
            *(const bf16x8*)&SMEM[r * 64 + ((c8 ^ (r & 7)) << 3)];
    }
}

// ---------------------------------------------------------------- output GEMM
__global__ __launch_bounds__(256) void out_gemm(
    const ushort* __restrict__ ctxb, const ushort* __restrict__ wob,
    const float* __restrict__ bo, float* __restrict__ out)
{
    __shared__ ushort As[128 * 32];
    __shared__ ushort Bs[128 * 32];
    f32x4 acc[4][4];
    const int m0 = blockIdx.x * 128;
    const int n0 = blockIdx.y * 128;
    gemm_bt_core<1024>(ctxb, wob, m0, n0, As, Bs, acc);

    const int lane = threadIdx.x & 63, wave = threadIdx.x >> 6;
    const int wm = wave >> 1, wn = wave & 1;
    const int col = lane & 15, rg = lane >> 4;
#pragma unroll
    for (int j = 0; j < 4; ++j) {
        const int n = n0 + wn * 64 + j * 16 + col;
        const float bias = bo[n];
#pragma unroll
        for (int i2 = 0; i2 < 4; ++i2) {
            const int mb2 = m0 + wm * 64 + i2 * 16 + rg * 4;
#pragma unroll
            for (int v = 0; v < 4; ++v)
                out[(uint64_t)(mb2 + v) * 1024 + n] = acc[i2][j][v] + bias;
        }
    }
}

// ---------------------------------------------------------------- launch
extern "C" void kernel_launch(void* const* d_in, const int* in_sizes, int n_in,
                              void* d_out, int out_size, void* d_ws, size_t ws_size,
                              hipStream_t stream)
{
    const float* x    = (const float*)d_in[0];
    const int*   mask = (const int*)d_in[1];
    const float* Wqkv = (const float*)d_in[2];
    const float* bqkv = (const float*)d_in[3];
    const float* Wo   = (const float*)d_in[4];
    const float* bo   = (const float*)d_in[5];
    float* out = (float*)d_out;

    char* p = (char*)d_ws;
    ushort* xb  = (ushort*)p; p += (size_t)8388608 * 2;   // x bf16 [8192][1024]
    ushort* wqb = (ushort*)p; p += (size_t)3145728 * 2;   // Wqkv bf16 [3072][1024]
    ushort* wob = (ushort*)p; p += (size_t)1048576 * 2;   // Wo bf16 [1024][1024]
    ushort* qo  = (ushort*)p; p += (size_t)8388608 * 2;   // Q bf16 [bh][s][64] (pre-scaled)
    ushort* ko  = (ushort*)p; p += (size_t)8388608 * 2;   // K bf16 [bh][s][64]
    ushort* vto = (ushort*)p; p += (size_t)8388608 * 2;   // V^T bf16 [bh][64][s]
    ushort* ctx = (ushort*)p; p += (size_t)8388608 * 2;   // ctx bf16 [8192][1024]
    uint32_t* mb = (uint32_t*)p;                          // packed mask bits (kt-major), 2 MB

    cvt_bf16<<<8192, 256, 0, stream>>>(x, xb, 2097152);
    cvt_bf16<<<3072, 256, 0, stream>>>(Wqkv, wqb, 786432);
    cvt_bf16<<<1024, 256, 0, stream>>>(Wo, wob, 262144);
    pack_mask<<<65536, 256, 0, stream>>>(mask, mb);
    qkv_gemm<<<dim3(64, 24), 256, 0, stream>>>(xb, wqb, bqkv, qo, ko, vto);
    attn_kernel<<<1024, 256, 0, stream>>>(qo, ko, vto, mb, ctx);
    out_gemm<<<dim3(64, 8), 256, 0, stream>>>(ctx, wob, bo, out);
}

// Round 7
// 367.426 us; speedup vs baseline: 1.7979x; 1.0302x over previous
//
#include <hip/hip_runtime.h>
#include <stdint.h>

// Problem constants
#define B_ 4
#define S_ 2048
#define E_ 1024
#define H_ 16
#define HD_ 64

typedef __attribute__((ext_vector_type(8))) short bf16x8;   // 8 bf16 = 4 VGPRs (MFMA A/B frag)
typedef __attribute__((ext_vector_type(4))) float f32x4;    // MFMA C/D frag

__device__ __forceinline__ ushort f2b(float f) {
    union { float f; uint32_t u; } c; c.f = f;
    return (ushort)((c.u + 0x8000u) >> 16);   // round-to-nearest (ties up)
}

// pack two f32 -> {bf16(a) lo, bf16(b) hi} in one u32 (2 add + 1 v_perm)
__device__ __forceinline__ uint32_t pkbf(float a, float b) {
    union { float f; uint32_t u; } ca, cb; ca.f = a; cb.f = b;
#if __has_builtin(__builtin_amdgcn_perm)
    return __builtin_amdgcn_perm(cb.u + 0x8000u, ca.u + 0x8000u, 0x07060302u);
#else
    return (uint32_t)f2b(a) | ((uint32_t)f2b(b) << 16);
#endif
}

#if __has_builtin(__builtin_amdgcn_exp2f)
#define EXP2(x) __builtin_amdgcn_exp2f(x)
#else
#define EXP2(x) exp2f(x)
#endif

// async global->LDS, 16B per lane; LDS dest = wave-uniform base + lane*16,
// global src = PER-LANE address (gather) -> source-side permutations are free.
__device__ __forceinline__ void gl2lds16(const ushort* g, const ushort* l) {
    __builtin_amdgcn_global_load_lds(
        (const __attribute__((address_space(1))) unsigned int*)g,
        (__attribute__((address_space(3))) unsigned int*)l,
        16, 0, 0);
}
__device__ __forceinline__ void gl2lds16raw(const void* g, const void* l) {
    __builtin_amdgcn_global_load_lds(
        (const __attribute__((address_space(1))) unsigned int*)g,
        (__attribute__((address_space(3))) unsigned int*)l,
        16, 0, 0);
}

// ---------------------------------------------------------------- fused converts
// x (2097152 float4) + Wqkv (786432) + Wo (262144) in one launch
__global__ __launch_bounds__(256) void cvt_all(
    const float* __restrict__ x, const float* __restrict__ wq, const float* __restrict__ wo,
    ushort* __restrict__ xb, ushort* __restrict__ wqb, ushort* __restrict__ wob) {
    int i = blockIdx.x * 256 + threadIdx.x;
    const float* src; ushort* dst; int off;
    if (i < 2097152)      { src = x;  dst = xb;  off = i; }
    else if (i < 2883584) { src = wq; dst = wqb; off = i - 2097152; }
    else                  { src = wo; dst = wob; off = i - 2883584; }
    float4 f = ((const float4*)src)[off];
    ushort4 o;
    o.x = f2b(f.x); o.y = f2b(f.y); o.z = f2b(f.z); o.w = f2b(f.w);
    ((ushort4*)dst)[off] = o;
}

// mask [B,S,S] int32 (0/1) -> bit-packed, kt-major:
// mb[((b*32 + kt)*2048 + q)*2 + w] bit c = mask[b][q][kt*64 + w*32 + c]
__global__ __launch_bounds__(256) void pack_mask(const int* __restrict__ mask,
                                                 uint32_t* __restrict__ mb) {
    int i = blockIdx.x * 256 + threadIdx.x;   // 16777216 threads
    unsigned long long bal = __ballot(mask[i] == 1);
    int lane = threadIdx.x & 63;
    if (lane < 2) {
        int b = i >> 22, q = (i >> 11) & 2047, c = i & 2047;
        int kt = c >> 6;
        mb[((uint64_t)(b * 32 + kt) * 2048 + q) * 2 + lane] =
            (lane == 0) ? (uint32_t)bal : (uint32_t)(bal >> 32);
    }
}

// ---------------------------------------------------------------- GEMM core
template <int KD>
__device__ __forceinline__ void gemm_bt_core(
    const ushort* __restrict__ A, const ushort* __restrict__ Bm,
    int m0, int n0, ushort* As, ushort* Bs, f32x4 (&acc)[4][4])
{
    const int tid  = threadIdx.x;
    const int lane = tid & 63;
    const int wave = tid >> 6;
    const int wm = wave >> 1, wn = wave & 1;
    const int fr = lane & 15;
    const int fk = (lane >> 4) * 8;
    const int lrow = lane >> 2;
    const int lk   = (lane & 3) * 8;

    const f32x4 fz = {0.f, 0.f, 0.f, 0.f};
#pragma unroll
    for (int i = 0; i < 4; ++i)
#pragma unroll
        for (int j = 0; j < 4; ++j) acc[i][j] = fz;

    for (int kt = 0; kt < KD / 32; ++kt) {
        const int k0 = kt * 32;
        __syncthreads();
#pragma unroll
        for (int t = 0; t < 2; ++t) {
            const int r0 = t * 64 + wave * 16;
            gl2lds16(&A [(uint64_t)(m0 + r0 + lrow) * KD + k0 + lk], &As[r0 * 32]);
            gl2lds16(&Bm[(uint64_t)(n0 + r0 + lrow) * KD + k0 + lk], &Bs[r0 * 32]);
        }
        __syncthreads();
        bf16x8 af[4], bfr[4];
#pragma unroll
        for (int i = 0; i < 4; ++i)
            af[i] = *(const bf16x8*)&As[(wm * 64 + i * 16 + fr) * 32 + fk];
#pragma unroll
        for (int j = 0; j < 4; ++j)
            bfr[j] = *(const bf16x8*)&Bs[(wn * 64 + j * 16 + fr) * 32 + fk];
#pragma unroll
        for (int i = 0; i < 4; ++i)
#pragma unroll
            for (int j = 0; j < 4; ++j)
                acc[i][j] = __builtin_amdgcn_mfma_f32_16x16x32_bf16(af[i], bfr[j], acc[i][j], 0, 0, 0);
    }
}

// ---------------------------------------------------------------- QKV GEMM
// Q pre-scaled by 0.125*log2(e): scores exit QK^T in log2 domain (exp2 softmax).
__global__ __launch_bounds__(256) void qkv_gemm(
    const ushort* __restrict__ xb, const ushort* __restrict__ wb,
    const float* __restrict__ bqkv,
    ushort* __restrict__ qo, ushort* __restrict__ ko, ushort* __restrict__ vto)
{
    __shared__ ushort As[128 * 32];
    __shared__ ushort Bs[128 * 32];
    f32x4 acc[4][4];
    const int m0 = blockIdx.x * 128;
    const int n0 = blockIdx.y * 128;
    gemm_bt_core<1024>(xb, wb, m0, n0, As, Bs, acc);

    const int lane = threadIdx.x & 63, wave = threadIdx.x >> 6;
    const int wm = wave >> 1, wn = wave & 1;
    const int col = lane & 15, rg = lane >> 4;
    const float QSC = 0.125f * 1.4426950408889634f;
#pragma unroll
    for (int j = 0; j < 4; ++j) {
        const int n = n0 + wn * 64 + j * 16 + col;
        const int h = n / 192, f = n % 192;
        const float bias = bqkv[n];
#pragma unroll
        for (int i2 = 0; i2 < 4; ++i2) {
            const int mbase = m0 + wm * 64 + i2 * 16 + rg * 4;
            if (f < 128) {
#pragma unroll
                for (int v = 0; v < 4; ++v) {
                    const int m = mbase + v;
                    const int b = m >> 11, s = m & 2047;
                    const float val = acc[i2][j][v] + bias;
                    if (f < 64) qo[((uint64_t)(b * 16 + h) * 2048 + s) * 64 + f]        = f2b(val * QSC);
                    else        ko[((uint64_t)(b * 16 + h) * 2048 + s) * 64 + (f - 64)] = f2b(val);
                }
            } else {
                const int b = mbase >> 11, s = mbase & 2047;
                ushort4 pk;
                pk.x = f2b(acc[i2][j][0] + bias);
                pk.y = f2b(acc[i2][j][1] + bias);
                pk.z = f2b(acc[i2][j][2] + bias);
                pk.w = f2b(acc[i2][j][3] + bias);
                *(ushort4*)&vto[((uint64_t)(b * 16 + h) * 64 + (f - 128)) * 2048 + s] = pk;
            }
        }
    }
}

// ---------------------------------------------------------------- flash attention v7
// v6 substrate (sigma-permuted K staging, register-only P, swizzled staging) +
// VALU thinning: exp2-domain scores (bare v_exp_f32), denominator via ones-MFMA
// (acc5), precomputed single-bit masks, v_perm bf16 pair packing.
__global__ __launch_bounds__(256, 3) void attn_kernel(
    const ushort* __restrict__ qa, const ushort* __restrict__ ka,
    const ushort* __restrict__ vta, const uint32_t* __restrict__ mbits,
    ushort* __restrict__ ctxo)
{
    __shared__ __align__(16) ushort SMEM[128 * 64];    // 16 KB: Q stage / ctx stage
    __shared__ __align__(16) ushort Ks[2][64 * 64];    // 16 KB dbuf K (sigma rows, swizzled units)
    __shared__ __align__(16) ushort Vts[2][64 * 64];   // 16 KB dbuf V^T [d][k] (swizzled units)
    __shared__ __align__(16) uint32_t Ms[2][256];      // 2 KB mask bits, dbuf

    const int bid = blockIdx.x;
    const int qb = bid & 15;                  // natural order: same-bh blocks adjacent
    const int bh = bid >> 4;
    const int b = bh >> 4;
    const int tid = threadIdx.x, lane = tid & 63, wave = tid >> 6;
    const int col = lane & 15, rg = lane >> 4;

    const uint64_t bhoff = (uint64_t)bh * (S_ * 64);
    const ushort* qp = qa + bhoff + (uint64_t)qb * 128 * 64;
    const ushort* kp = ka + bhoff;
    const ushort* vp = vta + bhoff;                       // [64][2048]
    const uint32_t* mkb = mbits + ((uint64_t)(b * 32) * 2048 + qb * 128) * 2;  // +kt*4096

    // staging geometry: 8 LDS rows / instruction; per-lane source gather
    const int lr = lane >> 3;                 // row within 8-row group (= r&7)
    const int usw = (lane & 7) ^ lr;          // XOR-swizzled 16B unit
    const int r0s = wave * 16 + lr;           // t=0 LDS row
    const int r1s = r0s + 8;                  // t=1 LDS row
    // sigma(r): bits (k2,jj,rg,v) -> (k2,rg,jj,v)
    const int sg0 = (r0s & 32) | ((r0s & 12) << 1) | ((r0s & 16) >> 2) | (r0s & 3);
    const int sg1 = (r1s & 32) | ((r1s & 12) << 1) | ((r1s & 16) >> 2) | (r1s & 3);
    const int kb0 = sg0 * 64 + usw * 8;       // K source offsets (element units)
    const int kb1 = sg1 * 64 + usw * 8;
    const int vb0 = r0s * 2048 + usw * 8;     // V source offsets (rows natural)
    const int vb1 = r1s * 2048 + usw * 8;
    const int ldst0 = wave * 1024;            // LDS dst (elements)
    const int ldst1 = ldst0 + 512;

    // stage Q tile (natural layout; read once into registers)
#pragma unroll
    for (int t4 = 0; t4 < 4; ++t4) {
        const int o = (wave * 4 + t4) * 512;
        gl2lds16(&qp[o + lane * 8], &SMEM[o]);
    }
    // prefetch kt=0 K/V/mask into buffer 0
    gl2lds16(&kp[kb0], &Ks[0][ldst0]);
    gl2lds16(&kp[kb1], &Ks[0][ldst1]);
    gl2lds16(&vp[vb0], &Vts[0][ldst0]);
    gl2lds16(&vp[vb1], &Vts[0][ldst1]);
    if (wave == 0) gl2lds16raw(mkb + lane * 4, &Ms[0][0]);
    __syncthreads();

    bf16x8 aq[2][2];                      // Q fragments (natural k order)
#pragma unroll
    for (int i = 0; i < 2; ++i)
#pragma unroll
        for (int k2 = 0; k2 < 2; ++k2)
            aq[i][k2] = *(const bf16x8*)&SMEM[(wave * 32 + i * 16 + col) * 64 + k2 * 32 + rg * 8];

    const f32x4 fz = {0.f, 0.f, 0.f, 0.f};
    f32x4 acc[4][2];                      // ctx^T: row=d, col=q (q = wave*32 + i*16 + col)
#pragma unroll
    for (int dt = 0; dt < 4; ++dt)
#pragma unroll
        for (int i = 0; i < 2; ++i) acc[dt][i] = fz;
    f32x4 acc5[2] = {fz, fz};             // softmax denominator via ones-MFMA

    bf16x8 vone;
#pragma unroll
    for (int e = 0; e < 8; ++e) vone[e] = (short)0x3F80;   // bf16 1.0

    // precomputed single-bit masks: bit position rg*8 + p*4 + v
    uint32_t bsel[2][4];
#pragma unroll
    for (int p = 0; p < 2; ++p)
#pragma unroll
        for (int v = 0; v < 4; ++v) bsel[p][v] = 1u << (rg * 8 + p * 4 + v);

    const int u0 = (rg ^ (col & 7)) << 3; // fragment read offset (k-units 0..31); other half ^32

    for (int kt = 0; kt < 32; ++kt) {
        const int buf = kt & 1;
        // issue prefetch for kt+1 into the other buffer (lands during this phase)
        if (kt < 31) {
            const int knext = (kt + 1) * 4096;
            gl2lds16(&kp[knext + kb0], &Ks[buf ^ 1][ldst0]);
            gl2lds16(&kp[knext + kb1], &Ks[buf ^ 1][ldst1]);
            gl2lds16(&vp[vb0 + (kt + 1) * 64], &Vts[buf ^ 1][ldst0]);
            gl2lds16(&vp[vb1 + (kt + 1) * 64], &Vts[buf ^ 1][ldst1]);
            if (wave == 0) gl2lds16raw(mkb + (uint64_t)(kt + 1) * 4096 + lane * 4,
                                       &Ms[buf ^ 1][0]);
        }

        // scores S^T (log2 domain) vs sigma-permuted keys
        f32x4 sc[2][4];
#pragma unroll
        for (int j = 0; j < 4; ++j) {
            bf16x8 bk0 = *(const bf16x8*)&Ks[buf][(j * 16 + col) * 64 + u0];
            bf16x8 bk1 = *(const bf16x8*)&Ks[buf][(j * 16 + col) * 64 + (u0 ^ 32)];
#pragma unroll
            for (int i = 0; i < 2; ++i) {
                f32x4 z = __builtin_amdgcn_mfma_f32_16x16x32_bf16(bk0, aq[i][0], fz, 0, 0, 0);
                sc[i][j] = __builtin_amdgcn_mfma_f32_16x16x32_bf16(bk1, aq[i][1], z, 0, 0, 0);
            }
        }

        // mask + exp2; pack P directly into PV B-fragments (registers only).
        // key held = (j&2)*16 + rg*8 + (j&1)*4 + v -> word j&2, bit rg*8+(j&1)*4+v.
        bf16x8 bp[2][2];
#pragma unroll
        for (int i = 0; i < 2; ++i) {
            const uint2 mw = *(const uint2*)&Ms[buf][(wave * 32 + i * 16 + col) * 2];
            union { uint32_t w[4]; bf16x8 v; } p0, p1;
#pragma unroll
            for (int j = 0; j < 4; ++j) {
                const uint32_t w = (j & 2) ? mw.y : mw.x;
                const int p = j & 1;
                float pe[4];
#pragma unroll
                for (int v = 0; v < 4; ++v) {
                    const float s = (w & bsel[p][v]) ? 0.f : sc[i][j][v];
                    pe[v] = EXP2(s);
                }
                const uint32_t lo = pkbf(pe[0], pe[1]);
                const uint32_t hi = pkbf(pe[2], pe[3]);
                if (j < 2) { p0.w[p * 2] = lo; p0.w[p * 2 + 1] = hi; }
                else       { p1.w[p * 2] = lo; p1.w[p * 2 + 1] = hi; }
            }
            bp[i][0] = p0.v;
            bp[i][1] = p1.v;
        }

        // PV: acc[d][q] += Vt[d][k] * P[q][k]; denominator via ones-row MFMA
#pragma unroll
        for (int i = 0; i < 2; ++i) {
            acc5[i] = __builtin_amdgcn_mfma_f32_16x16x32_bf16(vone, bp[i][0], acc5[i], 0, 0, 0);
            acc5[i] = __builtin_amdgcn_mfma_f32_16x16x32_bf16(vone, bp[i][1], acc5[i], 0, 0, 0);
        }
#pragma unroll
        for (int dt = 0; dt < 4; ++dt) {
            bf16x8 av0 = *(const bf16x8*)&Vts[buf][(dt * 16 + col) * 64 + u0];
            bf16x8 av1 = *(const bf16x8*)&Vts[buf][(dt * 16 + col) * 64 + (u0 ^ 32)];
#pragma unroll
            for (int i = 0; i < 2; ++i) {
                acc[dt][i] = __builtin_amdgcn_mfma_f32_16x16x32_bf16(av0, bp[i][0], acc[dt][i], 0, 0, 0);
                acc[dt][i] = __builtin_amdgcn_mfma_f32_16x16x32_bf16(av1, bp[i][1], acc[dt][i], 0, 0, 0);
            }
        }
        __syncthreads();   // single barrier: drains kt+1 prefetch (full phase old) + LDS reads
    }

    // 1/l per q=col lane: every row of acc5 equals the denominator (ones-matrix rows)
    float linv[2];
#pragma unroll
    for (int i = 0; i < 2; ++i) linv[i] = 1.0f / acc5[i][0];

    // transpose ctx^T back through SMEM (swizzled) for coalesced global store
#pragma unroll
    for (int dt = 0; dt < 4; ++dt)
#pragma unroll
        for (int i = 0; i < 2; ++i) {
            const int q = wave * 32 + i * 16 + col;
            const int d = dt * 16 + rg * 4;
            const int gg = (d >> 3) ^ (q & 7);
            ushort4 pk;
            pk.x = f2b(acc[dt][i][0] * linv[i]);
            pk.y = f2b(acc[dt][i][1] * linv[i]);
            pk.z = f2b(acc[dt][i][2] * linv[i]);
            pk.w = f2b(acc[dt][i][3] * linv[i]);
            *(ushort4*)&SMEM[q * 64 + gg * 8 + (d & 7)] = pk;
        }
    __syncthreads();
    const int h = bh & 15;
    const uint64_t obase = (uint64_t)(b * S_ + qb * 128) * E_ + (uint64_t)h * 64;
#pragma unroll
    for (int t4 = 0; t4 < 4; ++t4) {
        const int id = tid + t4 * 256;
        const int r = id >> 3, c8 = id & 7;
        *(bf16x8*)&ctxo[obase + (uint64_t)r * E_ + c8 * 8] =
            *(const bf16x8*)&SMEM[r * 64 + ((c8 ^ (r & 7)) << 3)];
    }
}

// ---------------------------------------------------------------- output GEMM
__global__ __launch_bounds__(256) void out_gemm(
    const ushort* __restrict__ ctxb, const ushort* __restrict__ wob,
    const float* __restrict__ bo, float* __restrict__ out)
{
    __shared__ ushort As[128 * 32];
    __shared__ ushort Bs[128 * 32];
    f32x4 acc[4][4];
    const int m0 = blockIdx.x * 128;
    const int n0 = blockIdx.y * 128;
    gemm_bt_core<1024>(ctxb, wob, m0, n0, As, Bs, acc);

    const int lane = threadIdx.x & 63, wave = threadIdx.x >> 6;
    const int wm = wave >> 1, wn = wave & 1;
    const int col = lane & 15, rg = lane >> 4;
#pragma unroll
    for (int j = 0; j < 4; ++j) {
        const int n = n0 + wn * 64 + j * 16 + col;
        const float bias = bo[n];
#pragma unroll
        for (int i2 = 0; i2 < 4; ++i2) {
            const int mb2 = m0 + wm * 64 + i2 * 16 + rg * 4;
#pragma unroll
            for (int v = 0; v < 4; ++v)
                out[(uint64_t)(mb2 + v) * 1024 + n] = acc[i2][j][v] + bias;
        }
    }
}

// ---------------------------------------------------------------- launch
extern "C" void kernel_launch(void* const* d_in, const int* in_sizes, int n_in,
                              void* d_out, int out_size, void* d_ws, size_t ws_size,
                              hipStream_t stream)
{
    const float* x    = (const float*)d_in[0];
    const int*   mask = (const int*)d_in[1];
    const float* Wqkv = (const float*)d_in[2];
    const float* bqkv = (const float*)d_in[3];
    const float* Wo   = (const float*)d_in[4];
    const float* bo   = (const float*)d_in[5];
    float* out = (float*)d_out;

    char* p = (char*)d_ws;
    ushort* xb  = (ushort*)p; p += (size_t)8388608 * 2;   // x bf16 [8192][1024]
    ushort* wqb = (ushort*)p; p += (size_t)3145728 * 2;   // Wqkv bf16 [3072][1024]
    ushort* wob = (ushort*)p; p += (size_t)1048576 * 2;   // Wo bf16 [1024][1024]
    ushort* qo  = (ushort*)p; p += (size_t)8388608 * 2;   // Q bf16 (log2-domain prescale)
    ushort* ko  = (ushort*)p; p += (size_t)8388608 * 2;   // K bf16 [bh][s][64]
    ushort* vto = (ushort*)p; p += (size_t)8388608 * 2;   // V^T bf16 [bh][64][s]
    ushort* ctx = (ushort*)p; p += (size_t)8388608 * 2;   // ctx bf16 [8192][1024]
    uint32_t* mb = (uint32_t*)p;                          // packed mask bits (kt-major), 2 MB

    cvt_all<<<12288, 256, 0, stream>>>(x, Wqkv, Wo, xb, wqb, wob);
    pack_mask<<<65536, 256, 0, stream>>>(mask, mb);
    qkv_gemm<<<dim3(64, 24), 256, 0, stream>>>(xb, wqb, bqkv, qo, ko, vto);
    attn_kernel<<<1024, 256, 0, stream>>>(qo, ko, vto, mb, ctx);
    out_gemm<<<dim3(64, 8), 256, 0, stream>>>(ctx, wob, bo, out);
}